// Round 1
// baseline (3785.455 us; speedup 1.0000x reference)
//
#include <hip/hip_runtime.h>
#include <math.h>

#define T_ 2048
#define D_ 2048
#define H_ 16
#define KVH_ 4
#define HD_ 128
#define E_ 8
#define I_ 1024
#define NQ_ 2048   // H_*HD_
#define NKV_ 512   // KVH_*HD_
#define LDT 68     // padded LDS tile stride (16B-aligned float4 reads, few conflicts)

__device__ __forceinline__ float4 f4zero() { float4 z; z.x = z.y = z.z = z.w = 0.f; return z; }

// ---------------- RMSNorm: one block per token ----------------
__global__ __launch_bounds__(256) void rmsnorm_k(const float* __restrict__ x,
                                                 const float* __restrict__ w,
                                                 float* __restrict__ y) {
  int t = blockIdx.x;
  int tid = threadIdx.x;
  const float* xr = x + (size_t)t * D_;
  float4 a = *(const float4*)&xr[tid * 8];
  float4 b = *(const float4*)&xr[tid * 8 + 4];
  float v[8] = {a.x, a.y, a.z, a.w, b.x, b.y, b.z, b.w};
  float ss = 0.f;
#pragma unroll
  for (int i = 0; i < 8; i++) ss += v[i] * v[i];
#pragma unroll
  for (int off = 32; off >= 1; off >>= 1) ss += __shfl_xor(ss, off, 64);
  __shared__ float part[4];
  __shared__ float scsh;
  if ((tid & 63) == 0) part[tid >> 6] = ss;
  __syncthreads();
  if (tid == 0) scsh = rsqrtf((part[0] + part[1] + part[2] + part[3]) * (1.0f / D_) + 1e-6f);
  __syncthreads();
  float sc = scsh;
  float4 w0 = *(const float4*)&w[tid * 8];
  float4 w1 = *(const float4*)&w[tid * 8 + 4];
  float wv[8] = {w0.x, w0.y, w0.z, w0.w, w1.x, w1.y, w1.z, w1.w};
  float* yr = y + (size_t)t * D_;
  float4 o0, o1;
  o0.x = v[0] * sc * wv[0]; o0.y = v[1] * sc * wv[1];
  o0.z = v[2] * sc * wv[2]; o0.w = v[3] * sc * wv[3];
  o1.x = v[4] * sc * wv[4]; o1.y = v[5] * sc * wv[5];
  o1.z = v[6] * sc * wv[6]; o1.w = v[7] * sc * wv[7];
  *(float4*)&yr[tid * 8] = o0;
  *(float4*)&yr[tid * 8 + 4] = o1;
}

// ---------------- Generic 64x64x16 f32 GEMM, C = A@B + bias ----------------
__global__ __launch_bounds__(256) void gemm_bias_k(const float* __restrict__ A,
                                                   const float* __restrict__ B,
                                                   const float* __restrict__ bias,
                                                   float* __restrict__ C, int N, int Kd) {
  __shared__ float As[16 * LDT];  // [k][m]
  __shared__ float Bs[16 * LDT];  // [k][n]
  int tid = threadIdx.x;
  int tx = tid & 15, ty = tid >> 4;
  int m0 = blockIdx.x * 64, n0 = blockIdx.y * 64;
  int lm = tid >> 2, lkq = (tid & 3) << 2;
  int lk = tid >> 4, lnq = (tid & 15) << 2;
  const float* arow = A + (size_t)(m0 + lm) * Kd + lkq;
  const float* brow = B + (size_t)lk * N + n0 + lnq;
  float acc[4][4] = {};
  for (int k0 = 0; k0 < Kd; k0 += 16) {
    float4 av = *(const float4*)(arow + k0);
    float4 bv = *(const float4*)(brow + (size_t)k0 * N);
    As[(lkq + 0) * LDT + lm] = av.x;
    As[(lkq + 1) * LDT + lm] = av.y;
    As[(lkq + 2) * LDT + lm] = av.z;
    As[(lkq + 3) * LDT + lm] = av.w;
    *(float4*)&Bs[lk * LDT + lnq] = bv;
    __syncthreads();
#pragma unroll
    for (int kk = 0; kk < 16; kk++) {
      float4 a4 = *(const float4*)&As[kk * LDT + (ty << 2)];
      float4 b4 = *(const float4*)&Bs[kk * LDT + (tx << 2)];
      float aa[4] = {a4.x, a4.y, a4.z, a4.w};
      float bb[4] = {b4.x, b4.y, b4.z, b4.w};
#pragma unroll
      for (int i = 0; i < 4; i++)
#pragma unroll
        for (int j = 0; j < 4; j++) acc[i][j] += aa[i] * bb[j];
    }
    __syncthreads();
  }
  float4 bb4 = *(const float4*)&bias[n0 + (tx << 2)];
  float bias4[4] = {bb4.x, bb4.y, bb4.z, bb4.w};
#pragma unroll
  for (int i = 0; i < 4; i++) {
    float4 o;
    o.x = acc[i][0] + bias4[0];
    o.y = acc[i][1] + bias4[1];
    o.z = acc[i][2] + bias4[2];
    o.w = acc[i][3] + bias4[3];
    *(float4*)&C[(size_t)(m0 + (ty << 2) + i) * N + n0 + (tx << 2)] = o;
  }
}

// ---------------- GEMM with residual add: C = A@B + R ----------------
__global__ __launch_bounds__(256) void gemm_res_k(const float* __restrict__ A,
                                                  const float* __restrict__ B,
                                                  const float* __restrict__ R,
                                                  float* __restrict__ C, int N, int Kd) {
  __shared__ float As[16 * LDT];
  __shared__ float Bs[16 * LDT];
  int tid = threadIdx.x;
  int tx = tid & 15, ty = tid >> 4;
  int m0 = blockIdx.x * 64, n0 = blockIdx.y * 64;
  int lm = tid >> 2, lkq = (tid & 3) << 2;
  int lk = tid >> 4, lnq = (tid & 15) << 2;
  const float* arow = A + (size_t)(m0 + lm) * Kd + lkq;
  const float* brow = B + (size_t)lk * N + n0 + lnq;
  float acc[4][4] = {};
  for (int k0 = 0; k0 < Kd; k0 += 16) {
    float4 av = *(const float4*)(arow + k0);
    float4 bv = *(const float4*)(brow + (size_t)k0 * N);
    As[(lkq + 0) * LDT + lm] = av.x;
    As[(lkq + 1) * LDT + lm] = av.y;
    As[(lkq + 2) * LDT + lm] = av.z;
    As[(lkq + 3) * LDT + lm] = av.w;
    *(float4*)&Bs[lk * LDT + lnq] = bv;
    __syncthreads();
#pragma unroll
    for (int kk = 0; kk < 16; kk++) {
      float4 a4 = *(const float4*)&As[kk * LDT + (ty << 2)];
      float4 b4 = *(const float4*)&Bs[kk * LDT + (tx << 2)];
      float aa[4] = {a4.x, a4.y, a4.z, a4.w};
      float bb[4] = {b4.x, b4.y, b4.z, b4.w};
#pragma unroll
      for (int i = 0; i < 4; i++)
#pragma unroll
        for (int j = 0; j < 4; j++) acc[i][j] += aa[i] * bb[j];
    }
    __syncthreads();
  }
#pragma unroll
  for (int i = 0; i < 4; i++) {
    size_t off = (size_t)(m0 + (ty << 2) + i) * N + n0 + (tx << 2);
    float4 rv = *(const float4*)&R[off];
    float4 o;
    o.x = acc[i][0] + rv.x;
    o.y = acc[i][1] + rv.y;
    o.z = acc[i][2] + rv.z;
    o.w = acc[i][3] + rv.w;
    *(float4*)&C[off] = o;
  }
}

// ---------------- RoPE (in-place), half-split pairs (i, i+64) ----------------
__global__ __launch_bounds__(256) void rope_k(float* __restrict__ buf,
                                              const int* __restrict__ pos, int nh) {
  int id = blockIdx.x * 256 + threadIdx.x;
  int i = id & 63;
  int hh = (id >> 6) & (nh - 1);
  int t = id / (nh * 64);
  float p = (float)pos[t];
  // inv_freq = THETA^(-i/64) = exp(-i * ln(1e6)/64)
  float f = p * expf(-0.21586735246819178f * (float)i);
  float s, c;
  sincosf(f, &s, &c);
  size_t base = (size_t)t * (nh * 128) + hh * 128 + i;
  float x1 = buf[base], x2 = buf[base + 64];
  buf[base] = x1 * c - x2 * s;
  buf[base + 64] = x2 * c + x1 * s;
}

// ---------------- Causal GQA flash attention ----------------
// grid: (T/16, H). block 256. 16 q-rows x 32-key tiles, online softmax.
__global__ __launch_bounds__(256) void attn_k(const float* __restrict__ Q,
                                              const float* __restrict__ Kb,
                                              const float* __restrict__ Vb,
                                              float* __restrict__ O) {
  __shared__ float Qs[16 * 132];
  __shared__ float Ks[32 * 132];
  __shared__ float Vs[32 * 132];
  __shared__ float S[16 * 33];
  __shared__ float msh[16], lsh[16], ash[16];
  int tid = threadIdx.x;
  int h = blockIdx.y;
  int t0 = blockIdx.x * 16;
  int kvh = h >> 2;  // rep = H/KVH = 4
  const float scale = 0.08838834764831845f;  // 1/sqrt(128)
#pragma unroll
  for (int i = 0; i < 8; i++) {
    int idx = tid + i * 256;
    int r = idx >> 7, d = idx & 127;
    Qs[r * 132 + d] = Q[(size_t)(t0 + r) * NQ_ + h * 128 + d] * scale;
  }
  if (tid < 16) { msh[tid] = -INFINITY; lsh[tid] = 0.f; }
  float acc[8] = {};
  int r = tid & 15;
  int dbase = (tid >> 4) << 3;
  int k1 = tid >> 4;
  int nkt = (t0 + 15) / 32 + 1;
  for (int kt = 0; kt < nkt; kt++) {
    int s0 = kt * 32;
    __syncthreads();  // protect Ks/Vs/S from previous iteration readers
#pragma unroll
    for (int i = 0; i < 16; i++) {
      int idx = tid + i * 256;
      int ss = idx >> 7, d = idx & 127;
      Ks[ss * 132 + d] = Kb[(size_t)(s0 + ss) * NKV_ + kvh * 128 + d];
      Vs[ss * 132 + d] = Vb[(size_t)(s0 + ss) * NKV_ + kvh * 128 + d];
    }
    __syncthreads();
    {  // scores: 2 per thread
      float s1 = 0.f, s2 = 0.f;
      int k2 = k1 + 16;
#pragma unroll
      for (int dq = 0; dq < 128; dq += 4) {
        float4 qv = *(const float4*)&Qs[r * 132 + dq];
        float4 ka = *(const float4*)&Ks[k1 * 132 + dq];
        float4 kb2 = *(const float4*)&Ks[k2 * 132 + dq];
        s1 += qv.x * ka.x + qv.y * ka.y + qv.z * ka.z + qv.w * ka.w;
        s2 += qv.x * kb2.x + qv.y * kb2.y + qv.z * kb2.z + qv.w * kb2.w;
      }
      int tq = t0 + r;
      S[r * 33 + k1] = (s0 + k1 <= tq) ? s1 : -INFINITY;
      S[r * 33 + k2] = (s0 + k2 <= tq) ? s2 : -INFINITY;
    }
    __syncthreads();
    if (tid < 16) {  // per-row online softmax update
      float m_old = msh[tid];
      float mloc = -INFINITY;
#pragma unroll
      for (int k = 0; k < 32; k++) mloc = fmaxf(mloc, S[tid * 33 + k]);
      float m_new = fmaxf(m_old, mloc);
      float alpha = expf(m_old - m_new);  // first tile: exp(-inf)=0
      float lsum = 0.f;
#pragma unroll
      for (int k = 0; k < 32; k++) {
        float pv = expf(S[tid * 33 + k] - m_new);  // masked: exp(-inf)=0
        S[tid * 33 + k] = pv;
        lsum += pv;
      }
      msh[tid] = m_new;
      lsh[tid] = lsh[tid] * alpha + lsum;
      ash[tid] = alpha;
    }
    __syncthreads();
    float alpha = ash[r];
#pragma unroll
    for (int j = 0; j < 8; j++) acc[j] *= alpha;
#pragma unroll
    for (int k = 0; k < 32; k++) {
      float pv = S[r * 33 + k];
      float4 v0 = *(const float4*)&Vs[k * 132 + dbase];
      float4 v1 = *(const float4*)&Vs[k * 132 + dbase + 4];
      acc[0] += pv * v0.x; acc[1] += pv * v0.y;
      acc[2] += pv * v0.z; acc[3] += pv * v0.w;
      acc[4] += pv * v1.x; acc[5] += pv * v1.y;
      acc[6] += pv * v1.z; acc[7] += pv * v1.w;
    }
  }
  float invl = 1.0f / lsh[r];
  size_t ob = (size_t)(t0 + r) * NQ_ + h * 128 + dbase;
#pragma unroll
  for (int j = 0; j < 8; j++) O[ob + j] = acc[j] * invl;
}

// ---------------- Router: logits, softmax, top-2, normalized weights ----------------
__global__ __launch_bounds__(256) void router_k(const float* __restrict__ X,
                                                const float* __restrict__ GW,
                                                int* __restrict__ tids,
                                                float* __restrict__ tws) {
  int t = blockIdx.x;
  int tid = threadIdx.x;
  const float* xr = X + (size_t)t * D_ + tid * 8;
  float4 a = *(const float4*)xr;
  float4 b = *(const float4*)(xr + 4);
  float xv[8] = {a.x, a.y, a.z, a.w, b.x, b.y, b.z, b.w};
  float acc[8] = {};
  const float* g = GW + (size_t)tid * 64;  // 8 rows x 8 experts, contiguous
#pragma unroll
  for (int rrow = 0; rrow < 8; rrow++) {
    float4 g0 = *(const float4*)(g + rrow * 8);
    float4 g1 = *(const float4*)(g + rrow * 8 + 4);
    float xs = xv[rrow];
    acc[0] += xs * g0.x; acc[1] += xs * g0.y; acc[2] += xs * g0.z; acc[3] += xs * g0.w;
    acc[4] += xs * g1.x; acc[5] += xs * g1.y; acc[6] += xs * g1.z; acc[7] += xs * g1.w;
  }
#pragma unroll
  for (int e = 0; e < 8; e++)
#pragma unroll
    for (int off = 32; off >= 1; off >>= 1) acc[e] += __shfl_xor(acc[e], off, 64);
  __shared__ float part[4][8];
  if ((tid & 63) == 0)
#pragma unroll
    for (int e = 0; e < 8; e++) part[tid >> 6][e] = acc[e];
  __syncthreads();
  if (tid == 0) {
    float lg[8];
#pragma unroll
    for (int e = 0; e < 8; e++) lg[e] = part[0][e] + part[1][e] + part[2][e] + part[3][e];
    int i1 = 0;
    for (int e = 1; e < 8; e++) if (lg[e] > lg[i1]) i1 = e;
    int i2 = (i1 == 0) ? 1 : 0;
    for (int e = 0; e < 8; e++) if (e != i1 && lg[e] > lg[i2]) i2 = e;
    float e2 = expf(lg[i2] - lg[i1]);  // softmax-denominators cancel in renorm
    float s = 1.0f + e2;
    tids[t * 2] = i1; tids[t * 2 + 1] = i2;
    tws[t * 2] = 1.0f / s; tws[t * 2 + 1] = e2 / s;
  }
}

// ---------------- Build per-expert compacted slot lists (single block) ----------------
__global__ __launch_bounds__(256) void route_build_k(const int* __restrict__ tids,
                                                     const float* __restrict__ tws,
                                                     int* __restrict__ offs,
                                                     int* __restrict__ ptok,
                                                     float* __restrict__ pw) {
  __shared__ int cnt[8];
  __shared__ int cur[8];
  int tid = threadIdx.x;
  if (tid < 8) cnt[tid] = 0;
  __syncthreads();
  for (int s = tid; s < T_ * 2; s += 256) atomicAdd(&cnt[tids[s]], 1);
  __syncthreads();
  if (tid == 0) {
    int o = 0;
    for (int e = 0; e < 8; e++) { cur[e] = o; offs[e] = o; o += cnt[e]; }
    offs[8] = o;  // == 4096
  }
  __syncthreads();
  for (int s = tid; s < T_ * 2; s += 256) {
    int e = tids[s];
    int p = atomicAdd(&cur[e], 1);
    ptok[p] = s >> 1;
    pw[p] = tws[s];
  }
}

// ---------------- MoE gate+up with gathered rows, fused SwiGLU ----------------
// grid (64, I/64, E); blocks past the expert's row count exit.
__global__ __launch_bounds__(256) void moe_gateup_k(const float* __restrict__ X,
                                                    const float* __restrict__ Wg,
                                                    const float* __restrict__ Wu,
                                                    const int* __restrict__ offs,
                                                    const int* __restrict__ ptok,
                                                    float* __restrict__ FF) {
  int e = blockIdx.z;
  int off = offs[e], end = offs[e + 1];
  int row0 = off + blockIdx.x * 64;
  if (row0 >= end) return;
  int n0 = blockIdx.y * 64;
  __shared__ float As[16 * LDT];
  __shared__ float Bg[16 * LDT];
  __shared__ float Bu[16 * LDT];
  __shared__ int rowtok[64];
  int tid = threadIdx.x;
  if (tid < 64) rowtok[tid] = (row0 + tid < end) ? ptok[row0 + tid] : -1;
  __syncthreads();
  int tx = tid & 15, ty = tid >> 4;
  int lm = tid >> 2, lkq = (tid & 3) << 2;
  int lk = tid >> 4, lnq = (tid & 15) << 2;
  int myrow = rowtok[lm];
  const float* arow = (myrow >= 0) ? X + (size_t)myrow * D_ + lkq : nullptr;
  const float* bgrow = Wg + (size_t)e * D_ * I_ + (size_t)lk * I_ + n0 + lnq;
  const float* burow = Wu + (size_t)e * D_ * I_ + (size_t)lk * I_ + n0 + lnq;
  float accg[4][4] = {}, accu[4][4] = {};
  for (int k0 = 0; k0 < D_; k0 += 16) {
    float4 av = arow ? *(const float4*)(arow + k0) : f4zero();
    float4 bg = *(const float4*)(bgrow + (size_t)k0 * I_);
    float4 bu = *(const float4*)(burow + (size_t)k0 * I_);
    As[(lkq + 0) * LDT + lm] = av.x;
    As[(lkq + 1) * LDT + lm] = av.y;
    As[(lkq + 2) * LDT + lm] = av.z;
    As[(lkq + 3) * LDT + lm] = av.w;
    *(float4*)&Bg[lk * LDT + lnq] = bg;
    *(float4*)&Bu[lk * LDT + lnq] = bu;
    __syncthreads();
#pragma unroll
    for (int kk = 0; kk < 16; kk++) {
      float4 a4 = *(const float4*)&As[kk * LDT + (ty << 2)];
      float4 g4 = *(const float4*)&Bg[kk * LDT + (tx << 2)];
      float4 u4 = *(const float4*)&Bu[kk * LDT + (tx << 2)];
      float aa[4] = {a4.x, a4.y, a4.z, a4.w};
      float gg[4] = {g4.x, g4.y, g4.z, g4.w};
      float uu[4] = {u4.x, u4.y, u4.z, u4.w};
#pragma unroll
      for (int i = 0; i < 4; i++)
#pragma unroll
        for (int j = 0; j < 4; j++) {
          accg[i][j] += aa[i] * gg[j];
          accu[i][j] += aa[i] * uu[j];
        }
    }
    __syncthreads();
  }
#pragma unroll
  for (int i = 0; i < 4; i++) {
    int p = row0 + (ty << 2) + i;
    if (p >= end) continue;
    float4 o;
    o.x = (accg[i][0] / (1.f + expf(-accg[i][0]))) * accu[i][0];
    o.y = (accg[i][1] / (1.f + expf(-accg[i][1]))) * accu[i][1];
    o.z = (accg[i][2] / (1.f + expf(-accg[i][2]))) * accu[i][2];
    o.w = (accg[i][3] / (1.f + expf(-accg[i][3]))) * accu[i][3];
    *(float4*)&FF[(size_t)p * I_ + n0 + (tx << 2)] = o;
  }
}

// ---------------- MoE down proj, scaled atomic accumulate into output ----------------
// grid (64, D/64, E)
__global__ __launch_bounds__(256) void moe_down_k(const float* __restrict__ FF,
                                                  const float* __restrict__ Wd,
                                                  const int* __restrict__ offs,
                                                  const int* __restrict__ ptok,
                                                  const float* __restrict__ pw,
                                                  float* __restrict__ out) {
  int e = blockIdx.z;
  int off = offs[e], end = offs[e + 1];
  int row0 = off + blockIdx.x * 64;
  if (row0 >= end) return;
  int n0 = blockIdx.y * 64;
  __shared__ float As[16 * LDT];
  __shared__ float Bs[16 * LDT];
  int tid = threadIdx.x;
  int tx = tid & 15, ty = tid >> 4;
  int lm = tid >> 2, lkq = (tid & 3) << 2;
  int lk = tid >> 4, lnq = (tid & 15) << 2;
  int prow = row0 + lm;
  const float* arow = (prow < end) ? FF + (size_t)prow * I_ + lkq : nullptr;
  const float* brow = Wd + (size_t)e * I_ * D_ + (size_t)lk * D_ + n0 + lnq;
  float acc[4][4] = {};
  for (int k0 = 0; k0 < I_; k0 += 16) {
    float4 av = arow ? *(const float4*)(arow + k0) : f4zero();
    float4 bv = *(const float4*)(brow + (size_t)k0 * D_);
    As[(lkq + 0) * LDT + lm] = av.x;
    As[(lkq + 1) * LDT + lm] = av.y;
    As[(lkq + 2) * LDT + lm] = av.z;
    As[(lkq + 3) * LDT + lm] = av.w;
    *(float4*)&Bs[lk * LDT + lnq] = bv;
    __syncthreads();
#pragma unroll
    for (int kk = 0; kk < 16; kk++) {
      float4 a4 = *(const float4*)&As[kk * LDT + (ty << 2)];
      float4 b4 = *(const float4*)&Bs[kk * LDT + (tx << 2)];
      float aa[4] = {a4.x, a4.y, a4.z, a4.w};
      float bb[4] = {b4.x, b4.y, b4.z, b4.w};
#pragma unroll
      for (int i = 0; i < 4; i++)
#pragma unroll
        for (int j = 0; j < 4; j++) acc[i][j] += aa[i] * bb[j];
    }
    __syncthreads();
  }
#pragma unroll
  for (int i = 0; i < 4; i++) {
    int p = row0 + (ty << 2) + i;
    if (p >= end) continue;
    int tok = ptok[p];
    float w = pw[p];
    float* orow = out + (size_t)tok * D_ + n0 + (tx << 2);
    atomicAdd(&orow[0], acc[i][0] * w);
    atomicAdd(&orow[1], acc[i][1] * w);
    atomicAdd(&orow[2], acc[i][2] * w);
    atomicAdd(&orow[3], acc[i][3] * w);
  }
}

extern "C" void kernel_launch(void* const* d_in, const int* in_sizes, int n_in,
                              void* d_out, int out_size, void* d_ws, size_t ws_size,
                              hipStream_t stream) {
  const float* hs  = (const float*)d_in[0];
  const int*   pos = (const int*)d_in[1];
  const float* ln1 = (const float*)d_in[2];
  const float* ln2 = (const float*)d_in[3];
  const float* wq  = (const float*)d_in[4];
  const float* bq  = (const float*)d_in[5];
  const float* wk  = (const float*)d_in[6];
  const float* bk  = (const float*)d_in[7];
  const float* wv  = (const float*)d_in[8];
  const float* bvp = (const float*)d_in[9];
  const float* wo  = (const float*)d_in[10];
  const float* gw  = (const float*)d_in[11];
  const float* wg  = (const float*)d_in[12];
  const float* wu  = (const float*)d_in[13];
  const float* wd  = (const float*)d_in[14];
  float* out = (float*)d_out;

  // workspace layout (floats): needs ~58.8 MB
  float* ws   = (float*)d_ws;
  float* XN   = ws;                       // 4M: xn1, then reused as xn2
  float* Qb   = ws + (size_t)4194304;     // 4M: q, then reused as FF
  float* Kbuf = ws + (size_t)8388608;     // 1M
  float* Vbuf = ws + (size_t)9437184;     // 1M
  float* AT   = ws + (size_t)10485760;    // 4M
  float* FF   = Qb;
  int*   tids = (int*)(ws + (size_t)14680064);
  float* tws  = (float*)(tids + 4096);
  int*   offs = (int*)(tws + 4096);
  int*   ptok = offs + 16;
  float* pw   = (float*)(ptok + 4096);

  // 1. RMSNorm 1
  rmsnorm_k<<<T_, 256, 0, stream>>>(hs, ln1, XN);
  // 2. QKV projections
  gemm_bias_k<<<dim3(T_ / 64, NQ_ / 64), 256, 0, stream>>>(XN, wq, bq, Qb, NQ_, D_);
  gemm_bias_k<<<dim3(T_ / 64, NKV_ / 64), 256, 0, stream>>>(XN, wk, bk, Kbuf, NKV_, D_);
  gemm_bias_k<<<dim3(T_ / 64, NKV_ / 64), 256, 0, stream>>>(XN, wv, bvp, Vbuf, NKV_, D_);
  // 3. RoPE on q and k (in place)
  rope_k<<<(T_ * H_ * 64) / 256, 256, 0, stream>>>(Qb, pos, H_);
  rope_k<<<(T_ * KVH_ * 64) / 256, 256, 0, stream>>>(Kbuf, pos, KVH_);
  // 4. causal GQA attention
  attn_k<<<dim3(T_ / 16, H_), 256, 0, stream>>>(Qb, Kbuf, Vbuf, AT);
  // 5. output projection + residual -> d_out holds h
  gemm_res_k<<<dim3(T_ / 64, D_ / 64), 256, 0, stream>>>(AT, wo, hs, out, D_, NQ_);
  // 6. RMSNorm 2 (reads h from d_out)
  rmsnorm_k<<<T_, 256, 0, stream>>>(out, ln2, XN);
  // 7. router top-2 + build compacted expert lists
  router_k<<<T_, 256, 0, stream>>>(XN, gw, tids, tws);
  route_build_k<<<1, 256, 0, stream>>>(tids, tws, offs, ptok, pw);
  // 8. expert FFN: gate/up fused SwiGLU, then down proj accumulated into d_out
  moe_gateup_k<<<dim3(64, I_ / 64, E_), 256, 0, stream>>>(XN, wg, wu, offs, ptok, FF);
  moe_down_k<<<dim3(64, D_ / 64, E_), 256, 0, stream>>>(FF, wd, offs, ptok, pw, out);
}

// Round 2
// 2034.084 us; speedup vs baseline: 1.8610x; 1.8610x over previous
//
#include <hip/hip_runtime.h>
#include <math.h>

#define T_ 2048
#define D_ 2048
#define H_ 16
#define KVH_ 4
#define HD_ 128
#define E_ 8
#define I_ 1024
#define NQ_ 2048   // H_*HD_
#define NKV_ 512   // KVH_*HD_
#define QKVW_ 3072 // NQ_ + 2*NKV_

typedef unsigned short ushort_t;
typedef unsigned int uint_t;
typedef __attribute__((ext_vector_type(8))) short short8;
typedef __attribute__((ext_vector_type(4))) float f4v;

__device__ __forceinline__ ushort_t f2b(float x) {
  union { float f; uint_t u; } v; v.f = x;
  uint_t r = v.u + 0x7FFFu + ((v.u >> 16) & 1u);
  return (ushort_t)(r >> 16);
}
__device__ __forceinline__ float b2f(ushort_t b) {
  union { uint_t u; float f; } v; v.u = ((uint_t)b) << 16;
  return v.f;
}

#define GLD_LDS16(gp, lp)                                                      \
  __builtin_amdgcn_global_load_lds(                                            \
      (const __attribute__((address_space(1))) uint_t*)(gp),                   \
      (__attribute__((address_space(3))) uint_t*)(lp), 16, 0, 0)

// ---------------- transpose + f32->bf16 convert: out[C x R] = in[R x C]^T ----
__global__ __launch_bounds__(256) void tcvt_k(const float* __restrict__ in,
                                              ushort_t* __restrict__ out,
                                              int R, int C, long inB, long outB) {
  in += (size_t)blockIdx.z * inB;
  out += (size_t)blockIdx.z * outB;
  __shared__ float tile[32][33];
  int r0 = blockIdx.y * 32, c0 = blockIdx.x * 32;
  int tr = threadIdx.x >> 3, tc = (threadIdx.x & 7) * 4;
  float4 v = *(const float4*)&in[(size_t)(r0 + tr) * C + c0 + tc];
  tile[tr][tc] = v.x; tile[tr][tc + 1] = v.y;
  tile[tr][tc + 2] = v.z; tile[tr][tc + 3] = v.w;
  __syncthreads();
  ushort4 o;
  o.x = f2b(tile[tc + 0][tr]); o.y = f2b(tile[tc + 1][tr]);
  o.z = f2b(tile[tc + 2][tr]); o.w = f2b(tile[tc + 3][tr]);
  *(ushort4*)&out[(size_t)(c0 + tr) * R + r0 + tc] = o;
}

// ---------------- bias concat [bq | bk | bv] -> 3072 ----------------
__global__ __launch_bounds__(256) void bias_concat_k(const float* __restrict__ bq,
                                                     const float* __restrict__ bk,
                                                     const float* __restrict__ bv,
                                                     float* __restrict__ bc) {
  int i = blockIdx.x * 256 + threadIdx.x;
  bc[i] = i < NQ_ ? bq[i] : (i < NQ_ + NKV_ ? bk[i - NQ_] : bv[i - NQ_ - NKV_]);
}

// ---------------- RMSNorm: f32 out + bf16 out ----------------
__global__ __launch_bounds__(256) void rmsnorm_k(const float* __restrict__ x,
                                                 const float* __restrict__ w,
                                                 float* __restrict__ y,
                                                 ushort_t* __restrict__ yb) {
  int t = blockIdx.x;
  int tid = threadIdx.x;
  const float* xr = x + (size_t)t * D_;
  float4 a = *(const float4*)&xr[tid * 8];
  float4 b = *(const float4*)&xr[tid * 8 + 4];
  float v[8] = {a.x, a.y, a.z, a.w, b.x, b.y, b.z, b.w};
  float ss = 0.f;
#pragma unroll
  for (int i = 0; i < 8; i++) ss += v[i] * v[i];
#pragma unroll
  for (int off = 32; off >= 1; off >>= 1) ss += __shfl_xor(ss, off, 64);
  __shared__ float part[4];
  __shared__ float scsh;
  if ((tid & 63) == 0) part[tid >> 6] = ss;
  __syncthreads();
  if (tid == 0) scsh = rsqrtf((part[0] + part[1] + part[2] + part[3]) * (1.0f / D_) + 1e-6f);
  __syncthreads();
  float sc = scsh;
  float4 w0 = *(const float4*)&w[tid * 8];
  float4 w1 = *(const float4*)&w[tid * 8 + 4];
  float wv[8] = {w0.x, w0.y, w0.z, w0.w, w1.x, w1.y, w1.z, w1.w};
  float o[8];
#pragma unroll
  for (int i = 0; i < 8; i++) o[i] = v[i] * sc * wv[i];
  float* yr = y + (size_t)t * D_;
  *(float4*)&yr[tid * 8] = make_float4(o[0], o[1], o[2], o[3]);
  *(float4*)&yr[tid * 8 + 4] = make_float4(o[4], o[5], o[6], o[7]);
  ushort_t* ybr = yb + (size_t)t * D_;
  ushort4 p0, p1;
  p0.x = f2b(o[0]); p0.y = f2b(o[1]); p0.z = f2b(o[2]); p0.w = f2b(o[3]);
  p1.x = f2b(o[4]); p1.y = f2b(o[5]); p1.z = f2b(o[6]); p1.w = f2b(o[7]);
  *(ushort4*)&ybr[tid * 8] = p0;
  *(ushort4*)&ybr[tid * 8 + 4] = p1;
}

// ---------------- generic bf16 MFMA GEMM (m97 structure) ----------------
// 128x128 tile, BK=32, 4 waves each 64x64 (4x4 tiles of 16x16x32 MFMA).
// A: [M x Kd] bf16 row-major (optionally gathered rows via ptok),
// BT: [N x Kd] bf16 row-major (= B^T). C[m][n] = sum_k A[m][k]*BT[n][k].
// EPI: 0 = f32 out + bias[col]; 1 = f32 out + residual (aux at same index);
//      2 = bf16 out at row=slot (routed, masked); 3 = atomicAdd f32 out at
//          row=ptok[slot], scaled by aux[slot] (routed, masked).
template <int EPI, bool GATHER, bool DUAL>
__global__ __launch_bounds__(256) void gemm_bf16_k(
    const ushort_t* __restrict__ A, const ushort_t* __restrict__ BT0,
    const ushort_t* __restrict__ BT1, int Kd, int N, long bExpStride,
    float* __restrict__ Of, ushort_t* __restrict__ Ob0, ushort_t* __restrict__ Ob1,
    const float* __restrict__ aux, const int* __restrict__ offs,
    const int* __restrict__ ptok) {
  int e = blockIdx.z;
  int m0 = blockIdx.x * 128;
  int off = 0, end = 0x7fffffff;
  const ushort_t* BT = BT0;
  ushort_t* Ob = Ob0;
  int ny = blockIdx.y;
  if (DUAL) {
    int half = gridDim.y >> 1;
    if (ny >= half) { ny -= half; BT = BT1; Ob = Ob1; }
  }
  int n0 = ny * 128;
  if (offs) {
    off = offs[e];
    end = offs[e + 1];
    if (off + m0 >= end) return;
    BT += (size_t)e * bExpStride;
  }
  __shared__ __align__(16) ushort_t As[128 * 32];
  __shared__ __align__(16) ushort_t Bs[128 * 32];
  int tid = threadIdx.x;
  int lane = tid & 63, w = tid >> 6;
  int r1 = tid >> 2, kc = (tid & 3) << 3;
  size_t ar1, ar2;
  {
    int s1 = m0 + r1, s2 = m0 + r1 + 64;
    if (offs) {
      s1 = off + s1; if (s1 > end - 1) s1 = end - 1;
      s2 = off + s2; if (s2 > end - 1) s2 = end - 1;
      ar1 = GATHER ? (size_t)ptok[s1] : (size_t)s1;
      ar2 = GATHER ? (size_t)ptok[s2] : (size_t)s2;
    } else {
      ar1 = (size_t)s1; ar2 = (size_t)s2;
    }
  }
  const ushort_t* gA1 = A + ar1 * Kd + kc;
  const ushort_t* gA2 = A + ar2 * Kd + kc;
  const ushort_t* gB1 = BT + (size_t)(n0 + r1) * Kd + kc;
  const ushort_t* gB2 = gB1 + (size_t)64 * Kd;
  ushort_t* lA = As + (tid & 192) * 8;   // wave-uniform chunk base
  ushort_t* lB = Bs + (tid & 192) * 8;
  f4v acc[4][4] = {};
  int ml = lane & 15, q = lane >> 4;
  int wm = (w & 1) << 6, wn = (w >> 1) << 6;
  for (int k0 = 0; k0 < Kd; k0 += 32) {
    GLD_LDS16(gA1 + k0, lA);
    GLD_LDS16(gA2 + k0, lA + 2048);
    GLD_LDS16(gB1 + k0, lB);
    GLD_LDS16(gB2 + k0, lB + 2048);
    __syncthreads();
    short8 af[4], bf[4];
#pragma unroll
    for (int i = 0; i < 4; i++)
      af[i] = *(const short8*)&As[(wm + i * 16 + ml) * 32 + q * 8];
#pragma unroll
    for (int j = 0; j < 4; j++)
      bf[j] = *(const short8*)&Bs[(wn + j * 16 + ml) * 32 + q * 8];
#pragma unroll
    for (int i = 0; i < 4; i++)
#pragma unroll
      for (int j = 0; j < 4; j++)
        acc[i][j] = __builtin_amdgcn_mfma_f32_16x16x32_bf16(af[i], bf[j], acc[i][j], 0, 0, 0);
    __syncthreads();
  }
  // epilogue: reg r of tile (i,j) -> row = wm+i*16+q*4+r, col = wn+j*16+ml
#pragma unroll
  for (int i = 0; i < 4; i++) {
#pragma unroll
    for (int r = 0; r < 4; r++) {
      int lrow = wm + i * 16 + q * 4 + r;
      int grow = m0 + lrow;
      if (EPI == 0) {
        size_t base = (size_t)grow * N + n0 + wn + ml;
#pragma unroll
        for (int j = 0; j < 4; j++)
          Of[base + j * 16] = acc[i][j][r] + aux[n0 + wn + ml + j * 16];
      } else if (EPI == 1) {
        size_t base = (size_t)grow * N + n0 + wn + ml;
#pragma unroll
        for (int j = 0; j < 4; j++)
          Of[base + j * 16] = acc[i][j][r] + aux[base + j * 16];
      } else if (EPI == 2) {
        int slot = off + grow;
        if (slot < end) {
          size_t base = (size_t)slot * N + n0 + wn + ml;
#pragma unroll
          for (int j = 0; j < 4; j++) Ob[base + j * 16] = f2b(acc[i][j][r]);
        }
      } else {
        int slot = off + grow;
        if (slot < end) {
          int tok = ptok[slot];
          float wgt = aux[slot];
          size_t base = (size_t)tok * N + n0 + wn + ml;
#pragma unroll
          for (int j = 0; j < 4; j++)
            atomicAdd(&Of[base + j * 16], acc[i][j][r] * wgt);
        }
      }
    }
  }
}

// ---------------- RoPE (in-place in QKV buffer) ----------------
__global__ __launch_bounds__(256) void rope_k(float* __restrict__ buf,
                                              const int* __restrict__ pos,
                                              int nh, int colOff) {
  int id = blockIdx.x * 256 + threadIdx.x;
  int i = id & 63;
  int hh = (id >> 6) & (nh - 1);
  int t = id / (nh * 64);
  float p = (float)pos[t];
  float f = p * expf(-0.21586735246819178f * (float)i);
  float s, c;
  sincosf(f, &s, &c);
  size_t base = (size_t)t * QKVW_ + colOff + hh * 128 + i;
  float x1 = buf[base], x2 = buf[base + 64];
  buf[base] = x1 * c - x2 * s;
  buf[base + 64] = x2 * c + x1 * s;
}

// ---------------- causal GQA flash attention (f32 in, bf16 out) ----------------
__global__ __launch_bounds__(256) void attn_k(const float* __restrict__ QKV,
                                              ushort_t* __restrict__ O) {
  __shared__ float Qs[16 * 132];
  __shared__ float Ks[32 * 132];
  __shared__ float Vs[32 * 132];
  __shared__ float S[16 * 33];
  __shared__ float msh[16], lsh[16], ash[16];
  int tid = threadIdx.x;
  int h = blockIdx.y;
  int t0 = blockIdx.x * 16;
  int kvh = h >> 2;
  const float scale = 0.08838834764831845f;
#pragma unroll
  for (int i = 0; i < 8; i++) {
    int idx = tid + i * 256;
    int r = idx >> 7, d = idx & 127;
    Qs[r * 132 + d] = QKV[(size_t)(t0 + r) * QKVW_ + h * 128 + d] * scale;
  }
  if (tid < 16) { msh[tid] = -INFINITY; lsh[tid] = 0.f; }
  float acc[8] = {};
  int r = tid & 15;
  int dbase = (tid >> 4) << 3;
  int k1 = tid >> 4;
  int nkt = (t0 + 15) / 32 + 1;
  for (int kt = 0; kt < nkt; kt++) {
    int s0 = kt * 32;
    __syncthreads();
#pragma unroll
    for (int i = 0; i < 16; i++) {
      int idx = tid + i * 256;
      int ss = idx >> 7, d = idx & 127;
      Ks[ss * 132 + d] = QKV[(size_t)(s0 + ss) * QKVW_ + NQ_ + kvh * 128 + d];
      Vs[ss * 132 + d] = QKV[(size_t)(s0 + ss) * QKVW_ + NQ_ + NKV_ + kvh * 128 + d];
    }
    __syncthreads();
    {
      float s1 = 0.f, s2 = 0.f;
      int k2 = k1 + 16;
#pragma unroll
      for (int dq = 0; dq < 128; dq += 4) {
        float4 qv = *(const float4*)&Qs[r * 132 + dq];
        float4 ka = *(const float4*)&Ks[k1 * 132 + dq];
        float4 kb2 = *(const float4*)&Ks[k2 * 132 + dq];
        s1 += qv.x * ka.x + qv.y * ka.y + qv.z * ka.z + qv.w * ka.w;
        s2 += qv.x * kb2.x + qv.y * kb2.y + qv.z * kb2.z + qv.w * kb2.w;
      }
      int tq = t0 + r;
      S[r * 33 + k1] = (s0 + k1 <= tq) ? s1 : -INFINITY;
      S[r * 33 + k2] = (s0 + k2 <= tq) ? s2 : -INFINITY;
    }
    __syncthreads();
    if (tid < 16) {
      float m_old = msh[tid];
      float mloc = -INFINITY;
#pragma unroll
      for (int k = 0; k < 32; k++) mloc = fmaxf(mloc, S[tid * 33 + k]);
      float m_new = fmaxf(m_old, mloc);
      float alpha = expf(m_old - m_new);
      float lsum = 0.f;
#pragma unroll
      for (int k = 0; k < 32; k++) {
        float pv = expf(S[tid * 33 + k] - m_new);
        S[tid * 33 + k] = pv;
        lsum += pv;
      }
      msh[tid] = m_new;
      lsh[tid] = lsh[tid] * alpha + lsum;
      ash[tid] = alpha;
    }
    __syncthreads();
    float alpha = ash[r];
#pragma unroll
    for (int j = 0; j < 8; j++) acc[j] *= alpha;
#pragma unroll
    for (int k = 0; k < 32; k++) {
      float pv = S[r * 33 + k];
      float4 v0 = *(const float4*)&Vs[k * 132 + dbase];
      float4 v1 = *(const float4*)&Vs[k * 132 + dbase + 4];
      acc[0] += pv * v0.x; acc[1] += pv * v0.y;
      acc[2] += pv * v0.z; acc[3] += pv * v0.w;
      acc[4] += pv * v1.x; acc[5] += pv * v1.y;
      acc[6] += pv * v1.z; acc[7] += pv * v1.w;
    }
  }
  float invl = 1.0f / lsh[r];
  size_t ob = (size_t)(t0 + r) * NQ_ + h * 128 + dbase;
#pragma unroll
  for (int j = 0; j < 8; j++) O[ob + j] = f2b(acc[j] * invl);
}

// ---------------- router (f32 inputs -> exact top-2 vs reference) ----------------
__global__ __launch_bounds__(256) void router_k(const float* __restrict__ X,
                                                const float* __restrict__ GW,
                                                int* __restrict__ tids,
                                                float* __restrict__ tws) {
  int t = blockIdx.x;
  int tid = threadIdx.x;
  const float* xr = X + (size_t)t * D_ + tid * 8;
  float4 a = *(const float4*)xr;
  float4 b = *(const float4*)(xr + 4);
  float xv[8] = {a.x, a.y, a.z, a.w, b.x, b.y, b.z, b.w};
  float acc[8] = {};
  const float* g = GW + (size_t)tid * 64;
#pragma unroll
  for (int rrow = 0; rrow < 8; rrow++) {
    float4 g0 = *(const float4*)(g + rrow * 8);
    float4 g1 = *(const float4*)(g + rrow * 8 + 4);
    float xs = xv[rrow];
    acc[0] += xs * g0.x; acc[1] += xs * g0.y; acc[2] += xs * g0.z; acc[3] += xs * g0.w;
    acc[4] += xs * g1.x; acc[5] += xs * g1.y; acc[6] += xs * g1.z; acc[7] += xs * g1.w;
  }
#pragma unroll
  for (int e = 0; e < 8; e++)
#pragma unroll
    for (int off = 32; off >= 1; off >>= 1) acc[e] += __shfl_xor(acc[e], off, 64);
  __shared__ float part[4][8];
  if ((tid & 63) == 0)
#pragma unroll
    for (int e = 0; e < 8; e++) part[tid >> 6][e] = acc[e];
  __syncthreads();
  if (tid == 0) {
    float lg[8];
#pragma unroll
    for (int e = 0; e < 8; e++) lg[e] = part[0][e] + part[1][e] + part[2][e] + part[3][e];
    int i1 = 0;
    for (int e = 1; e < 8; e++) if (lg[e] > lg[i1]) i1 = e;
    int i2 = (i1 == 0) ? 1 : 0;
    for (int e = 0; e < 8; e++) if (e != i1 && lg[e] > lg[i2]) i2 = e;
    float e2 = expf(lg[i2] - lg[i1]);
    float s = 1.0f + e2;
    tids[t * 2] = i1; tids[t * 2 + 1] = i2;
    tws[t * 2] = 1.0f / s; tws[t * 2 + 1] = e2 / s;
  }
}

__global__ __launch_bounds__(256) void route_build_k(const int* __restrict__ tids,
                                                     const float* __restrict__ tws,
                                                     int* __restrict__ offs,
                                                     int* __restrict__ ptok,
                                                     float* __restrict__ pw) {
  __shared__ int cnt[8];
  __shared__ int cur[8];
  int tid = threadIdx.x;
  if (tid < 8) cnt[tid] = 0;
  __syncthreads();
  for (int s = tid; s < T_ * 2; s += 256) atomicAdd(&cnt[tids[s]], 1);
  __syncthreads();
  if (tid == 0) {
    int o = 0;
    for (int e = 0; e < 8; e++) { cur[e] = o; offs[e] = o; o += cnt[e]; }
    offs[8] = o;
  }
  __syncthreads();
  for (int s = tid; s < T_ * 2; s += 256) {
    int e = tids[s];
    int p = atomicAdd(&cur[e], 1);
    ptok[p] = s >> 1;
    pw[p] = tws[s];
  }
}

// ---------------- SwiGLU: FF = silu(G) * U (bf16) ----------------
__global__ __launch_bounds__(256) void swiglu_k(const ushort_t* __restrict__ G,
                                                const ushort_t* __restrict__ U,
                                                ushort_t* __restrict__ FF) {
  int i = (blockIdx.x * 256 + threadIdx.x) * 4;
  ushort4 g4 = *(const ushort4*)&G[i];
  ushort4 u4 = *(const ushort4*)&U[i];
  float g[4] = {b2f(g4.x), b2f(g4.y), b2f(g4.z), b2f(g4.w)};
  float u[4] = {b2f(u4.x), b2f(u4.y), b2f(u4.z), b2f(u4.w)};
  ushort4 o;
  o.x = f2b(g[0] / (1.f + expf(-g[0])) * u[0]);
  o.y = f2b(g[1] / (1.f + expf(-g[1])) * u[1]);
  o.z = f2b(g[2] / (1.f + expf(-g[2])) * u[2]);
  o.w = f2b(g[3] / (1.f + expf(-g[3])) * u[3]);
  *(ushort4*)&FF[i] = o;
}

extern "C" void kernel_launch(void* const* d_in, const int* in_sizes, int n_in,
                              void* d_out, int out_size, void* d_ws, size_t ws_size,
                              hipStream_t stream) {
  const float* hs  = (const float*)d_in[0];
  const int*   pos = (const int*)d_in[1];
  const float* ln1 = (const float*)d_in[2];
  const float* ln2 = (const float*)d_in[3];
  const float* wq  = (const float*)d_in[4];
  const float* bq  = (const float*)d_in[5];
  const float* wk  = (const float*)d_in[6];
  const float* bk  = (const float*)d_in[7];
  const float* wv  = (const float*)d_in[8];
  const float* bvp = (const float*)d_in[9];
  const float* wo  = (const float*)d_in[10];
  const float* gw  = (const float*)d_in[11];
  const float* wg  = (const float*)d_in[12];
  const float* wu  = (const float*)d_in[13];
  const float* wd  = (const float*)d_in[14];
  float* out = (float*)d_out;

  const size_t M = 1048576;
  float* ws = (float*)d_ws;
  float*    XN    = ws;                        // 4M f32
  float*    QKV   = ws + 4 * M;                // 6M f32 (region reused for G/U)
  ushort_t* G     = (ushort_t*)QKV;            // 4M bf16 (after attention done)
  ushort_t* U     = (ushort_t*)(ws + 6 * M);   // 4M bf16
  ushort_t* XNb   = (ushort_t*)(ws + 10 * M);  // 4M bf16
  ushort_t* ATb   = (ushort_t*)(ws + 12 * M);  // 4M bf16 (reused as FF)
  ushort_t* FF    = ATb;
  ushort_t* wqkvT = (ushort_t*)(ws + 14 * M);  // 3072x2048 bf16
  ushort_t* woT   = (ushort_t*)(ws + 17 * M);  // 2048x2048 bf16
  ushort_t* wgT   = (ushort_t*)(ws + 19 * M);  // 8x1024x2048 bf16
  ushort_t* wuT   = (ushort_t*)(ws + 27 * M);  // 8x1024x2048 bf16
  ushort_t* wdT   = (ushort_t*)(ws + 35 * M);  // 8x2048x1024 bf16
  float*    biasC = ws + 43 * M;               // 3072 f32
  int*      tids  = (int*)(biasC + 4096);
  float*    tws   = (float*)(tids + 4096);
  int*      offs  = (int*)(tws + 4096);
  int*      ptok  = offs + 16;
  float*    pw    = (float*)(ptok + 4096);

  // ---- weight pre-pass: transpose + bf16 convert ----
  tcvt_k<<<dim3(64, 64, 1), 256, 0, stream>>>(wq, wqkvT, 2048, 2048, 0, 0);
  tcvt_k<<<dim3(16, 64, 1), 256, 0, stream>>>(wk, wqkvT + (size_t)2048 * 2048, 2048, 512, 0, 0);
  tcvt_k<<<dim3(16, 64, 1), 256, 0, stream>>>(wv, wqkvT + (size_t)2560 * 2048, 2048, 512, 0, 0);
  tcvt_k<<<dim3(64, 64, 1), 256, 0, stream>>>(wo, woT, 2048, 2048, 0, 0);
  tcvt_k<<<dim3(32, 64, 8), 256, 0, stream>>>(wg, wgT, 2048, 1024, 2048L * 1024, 2048L * 1024);
  tcvt_k<<<dim3(32, 64, 8), 256, 0, stream>>>(wu, wuT, 2048, 1024, 2048L * 1024, 2048L * 1024);
  tcvt_k<<<dim3(64, 32, 8), 256, 0, stream>>>(wd, wdT, 1024, 2048, 1024L * 2048, 1024L * 2048);
  bias_concat_k<<<12, 256, 0, stream>>>(bq, bk, bvp, biasC);

  // ---- layer ----
  rmsnorm_k<<<T_, 256, 0, stream>>>(hs, ln1, XN, XNb);
  // fused QKV projection: [T x 3072] f32 = XNb @ [wq|wk|wv] + bias
  gemm_bf16_k<0, false, false><<<dim3(16, 24, 1), 256, 0, stream>>>(
      XNb, wqkvT, nullptr, D_, QKVW_, 0, QKV, nullptr, nullptr, biasC, nullptr, nullptr);
  rope_k<<<(T_ * H_ * 64) / 256, 256, 0, stream>>>(QKV, pos, H_, 0);
  rope_k<<<(T_ * KVH_ * 64) / 256, 256, 0, stream>>>(QKV, pos, KVH_, NQ_);
  attn_k<<<dim3(T_ / 16, H_), 256, 0, stream>>>(QKV, ATb);
  // O-projection + residual -> out holds h
  gemm_bf16_k<1, false, false><<<dim3(16, 16, 1), 256, 0, stream>>>(
      ATb, woT, nullptr, NQ_, D_, 0, out, nullptr, nullptr, hs, nullptr, nullptr);
  rmsnorm_k<<<T_, 256, 0, stream>>>(out, ln2, XN, XNb);
  router_k<<<T_, 256, 0, stream>>>(XN, gw, tids, tws);
  route_build_k<<<1, 256, 0, stream>>>(tids, tws, offs, ptok, pw);
  // routed gate+up in one launch (DUAL splits grid.y)
  gemm_bf16_k<2, true, true><<<dim3(32, 16, 8), 256, 0, stream>>>(
      XNb, wgT, wuT, D_, I_, 1024L * 2048, nullptr, G, U, nullptr, offs, ptok);
  swiglu_k<<<4096, 256, 0, stream>>>(G, U, FF);
  // routed down-proj, weighted atomic accumulate into out
  gemm_bf16_k<3, false, false><<<dim3(32, 16, 8), 256, 0, stream>>>(
      FF, wdT, nullptr, I_, D_, 1024L * 2048, out, nullptr, nullptr, pw, offs, ptok);
}

// Round 3
// 1102.131 us; speedup vs baseline: 3.4347x; 1.8456x over previous
//
#include <hip/hip_runtime.h>
#include <math.h>

#define T_ 2048
#define D_ 2048
#define H_ 16
#define KVH_ 4
#define HD_ 128
#define E_ 8
#define I_ 1024
#define NQ_ 2048   // H_*HD_
#define NKV_ 512   // KVH_*HD_
#define QKVW_ 3072 // NQ_ + 2*NKV_

typedef unsigned short ushort_t;
typedef unsigned int uint_t;
typedef __attribute__((ext_vector_type(8))) short short8;
typedef __attribute__((ext_vector_type(4))) float f4v;

__device__ __forceinline__ ushort_t f2b(float x) {
  union { float f; uint_t u; } v; v.f = x;
  uint_t r = v.u + 0x7FFFu + ((v.u >> 16) & 1u);
  return (ushort_t)(r >> 16);
}
__device__ __forceinline__ float b2f(ushort_t b) {
  union { uint_t u; float f; } v; v.u = ((uint_t)b) << 16;
  return v.f;
}

#define GLD_LDS16(gp, lp)                                                      \
  __builtin_amdgcn_global_load_lds(                                            \
      (const __attribute__((address_space(1))) uint_t*)(gp),                   \
      (__attribute__((address_space(3))) uint_t*)(lp), 16, 0, 0)

// ---------------- transpose + f32->bf16 convert: out[C x R] = in[R x C]^T ----
__global__ __launch_bounds__(256) void tcvt_k(const float* __restrict__ in,
                                              ushort_t* __restrict__ out,
                                              int R, int C, long inB, long outB) {
  in += (size_t)blockIdx.z * inB;
  out += (size_t)blockIdx.z * outB;
  __shared__ float tile[32][33];
  int r0 = blockIdx.y * 32, c0 = blockIdx.x * 32;
  int tr = threadIdx.x >> 3, tc = (threadIdx.x & 7) * 4;
  float4 v = *(const float4*)&in[(size_t)(r0 + tr) * C + c0 + tc];
  tile[tr][tc] = v.x; tile[tr][tc + 1] = v.y;
  tile[tr][tc + 2] = v.z; tile[tr][tc + 3] = v.w;
  __syncthreads();
  ushort4 o;
  o.x = f2b(tile[tc + 0][tr]); o.y = f2b(tile[tc + 1][tr]);
  o.z = f2b(tile[tc + 2][tr]); o.w = f2b(tile[tc + 3][tr]);
  *(ushort4*)&out[(size_t)(c0 + tr) * R + r0 + tc] = o;
}

// ---------------- bias concat [bq | bk | bv] -> 3072 ----------------
__global__ __launch_bounds__(256) void bias_concat_k(const float* __restrict__ bq,
                                                     const float* __restrict__ bk,
                                                     const float* __restrict__ bv,
                                                     float* __restrict__ bc) {
  int i = blockIdx.x * 256 + threadIdx.x;
  bc[i] = i < NQ_ ? bq[i] : (i < NQ_ + NKV_ ? bk[i - NQ_] : bv[i - NQ_ - NKV_]);
}

// ---------------- RMSNorm: optional f32 out + bf16 out ----------------
__global__ __launch_bounds__(256) void rmsnorm_k(const float* __restrict__ x,
                                                 const float* __restrict__ w,
                                                 float* __restrict__ y,
                                                 ushort_t* __restrict__ yb) {
  int t = blockIdx.x;
  int tid = threadIdx.x;
  const float* xr = x + (size_t)t * D_;
  float4 a = *(const float4*)&xr[tid * 8];
  float4 b = *(const float4*)&xr[tid * 8 + 4];
  float v[8] = {a.x, a.y, a.z, a.w, b.x, b.y, b.z, b.w};
  float ss = 0.f;
#pragma unroll
  for (int i = 0; i < 8; i++) ss += v[i] * v[i];
#pragma unroll
  for (int off = 32; off >= 1; off >>= 1) ss += __shfl_xor(ss, off, 64);
  __shared__ float part[4];
  __shared__ float scsh;
  if ((tid & 63) == 0) part[tid >> 6] = ss;
  __syncthreads();
  if (tid == 0) scsh = rsqrtf((part[0] + part[1] + part[2] + part[3]) * (1.0f / D_) + 1e-6f);
  __syncthreads();
  float sc = scsh;
  float4 w0 = *(const float4*)&w[tid * 8];
  float4 w1 = *(const float4*)&w[tid * 8 + 4];
  float wv[8] = {w0.x, w0.y, w0.z, w0.w, w1.x, w1.y, w1.z, w1.w};
  float o[8];
#pragma unroll
  for (int i = 0; i < 8; i++) o[i] = v[i] * sc * wv[i];
  if (y) {
    float* yr = y + (size_t)t * D_;
    *(float4*)&yr[tid * 8] = make_float4(o[0], o[1], o[2], o[3]);
    *(float4*)&yr[tid * 8 + 4] = make_float4(o[4], o[5], o[6], o[7]);
  }
  ushort_t* ybr = yb + (size_t)t * D_;
  ushort4 p0, p1;
  p0.x = f2b(o[0]); p0.y = f2b(o[1]); p0.z = f2b(o[2]); p0.w = f2b(o[3]);
  p1.x = f2b(o[4]); p1.y = f2b(o[5]); p1.z = f2b(o[6]); p1.w = f2b(o[7]);
  *(ushort4*)&ybr[tid * 8] = p0;
  *(ushort4*)&ybr[tid * 8 + 4] = p1;
}

// ---------------- generic bf16 MFMA GEMM (m97 structure) ----------------
template <int EPI, bool GATHER, bool DUAL>
__global__ __launch_bounds__(256) void gemm_bf16_k(
    const ushort_t* __restrict__ A, const ushort_t* __restrict__ BT0,
    const ushort_t* __restrict__ BT1, int Kd, int N, long bExpStride,
    float* __restrict__ Of, ushort_t* __restrict__ Ob0, ushort_t* __restrict__ Ob1,
    const float* __restrict__ aux, const int* __restrict__ offs,
    const int* __restrict__ ptok) {
  int e = blockIdx.z;
  int m0 = blockIdx.x * 128;
  int off = 0, end = 0x7fffffff;
  const ushort_t* BT = BT0;
  ushort_t* Ob = Ob0;
  int ny = blockIdx.y;
  if (DUAL) {
    int half = gridDim.y >> 1;
    if (ny >= half) { ny -= half; BT = BT1; Ob = Ob1; }
  }
  int n0 = ny * 128;
  if (offs) {
    off = offs[e];
    end = offs[e + 1];
    if (off + m0 >= end) return;
    BT += (size_t)e * bExpStride;
  }
  __shared__ __align__(16) ushort_t As[128 * 32];
  __shared__ __align__(16) ushort_t Bs[128 * 32];
  int tid = threadIdx.x;
  int lane = tid & 63, w = tid >> 6;
  int r1 = tid >> 2, kc = (tid & 3) << 3;
  size_t ar1, ar2;
  {
    int s1 = m0 + r1, s2 = m0 + r1 + 64;
    if (offs) {
      s1 = off + s1; if (s1 > end - 1) s1 = end - 1;
      s2 = off + s2; if (s2 > end - 1) s2 = end - 1;
      ar1 = GATHER ? (size_t)ptok[s1] : (size_t)s1;
      ar2 = GATHER ? (size_t)ptok[s2] : (size_t)s2;
    } else {
      ar1 = (size_t)s1; ar2 = (size_t)s2;
    }
  }
  const ushort_t* gA1 = A + ar1 * Kd + kc;
  const ushort_t* gA2 = A + ar2 * Kd + kc;
  const ushort_t* gB1 = BT + (size_t)(n0 + r1) * Kd + kc;
  const ushort_t* gB2 = gB1 + (size_t)64 * Kd;
  ushort_t* lA = As + (tid & 192) * 8;
  ushort_t* lB = Bs + (tid & 192) * 8;
  f4v acc[4][4] = {};
  int ml = lane & 15, q = lane >> 4;
  int wm = (w & 1) << 6, wn = (w >> 1) << 6;
  for (int k0 = 0; k0 < Kd; k0 += 32) {
    GLD_LDS16(gA1 + k0, lA);
    GLD_LDS16(gA2 + k0, lA + 2048);
    GLD_LDS16(gB1 + k0, lB);
    GLD_LDS16(gB2 + k0, lB + 2048);
    __syncthreads();
    short8 af[4], bf[4];
#pragma unroll
    for (int i = 0; i < 4; i++)
      af[i] = *(const short8*)&As[(wm + i * 16 + ml) * 32 + q * 8];
#pragma unroll
    for (int j = 0; j < 4; j++)
      bf[j] = *(const short8*)&Bs[(wn + j * 16 + ml) * 32 + q * 8];
#pragma unroll
    for (int i = 0; i < 4; i++)
#pragma unroll
      for (int j = 0; j < 4; j++)
        acc[i][j] = __builtin_amdgcn_mfma_f32_16x16x32_bf16(af[i], bf[j], acc[i][j], 0, 0, 0);
    __syncthreads();
  }
#pragma unroll
  for (int i = 0; i < 4; i++) {
#pragma unroll
    for (int r = 0; r < 4; r++) {
      int lrow = wm + i * 16 + q * 4 + r;
      int grow = m0 + lrow;
      if (EPI == 0) {
        size_t base = (size_t)grow * N + n0 + wn + ml;
#pragma unroll
        for (int j = 0; j < 4; j++)
          Of[base + j * 16] = acc[i][j][r] + aux[n0 + wn + ml + j * 16];
      } else if (EPI == 1) {
        size_t base = (size_t)grow * N + n0 + wn + ml;
#pragma unroll
        for (int j = 0; j < 4; j++)
          Of[base + j * 16] = acc[i][j][r] + aux[base + j * 16];
      } else if (EPI == 2) {
        int slot = off + grow;
        if (slot < end) {
          size_t base = (size_t)slot * N + n0 + wn + ml;
#pragma unroll
          for (int j = 0; j < 4; j++) Ob[base + j * 16] = f2b(acc[i][j][r]);
        }
      } else {
        int slot = off + grow;
        if (slot < end) {
          int tok = ptok[slot];
          float wgt = aux[slot];
          size_t base = (size_t)tok * N + n0 + wn + ml;
#pragma unroll
          for (int j = 0; j < 4; j++)
            atomicAdd(&Of[base + j * 16], acc[i][j][r] * wgt);
        }
      }
    }
  }
}

// ---------------- QKV prep: RoPE + bf16 + MFMA-friendly chunked layouts ----
// Qbh: [H][T/64][kb=4][64][32] (scaled); Kbh: [KVH][T/64][4][64][32];
// Vth: [KVH][T/64][kb2=2][128][32]  (V transposed: element (d, t)).
__global__ __launch_bounds__(256) void qkv_prep_k(const float* __restrict__ QKV,
                                                  const int* __restrict__ pos,
                                                  ushort_t* __restrict__ Qbh,
                                                  ushort_t* __restrict__ Kbh,
                                                  ushort_t* __restrict__ Vth) {
  int t = blockIdx.x;
  int u = blockIdx.y * 4 + (threadIdx.x >> 6);
  int i = threadIdx.x & 63;
  int ts = t >> 6, tr = t & 63;
  const float scale = 0.08838834764831845f;
  if (u < 16) {  // Q head u: rope + scale
    const float* src = QKV + (size_t)t * QKVW_ + u * 128;
    float x1 = src[i], x2 = src[i + 64];
    float p = (float)pos[t];
    float f = p * expf(-0.21586735246819178f * (float)i);
    float sn, cs; sincosf(f, &sn, &cs);
    float o1 = (x1 * cs - x2 * sn) * scale;
    float o2 = (x2 * cs + x1 * sn) * scale;
    ushort_t* dst = Qbh + (size_t)u * (T_ * 128) + (size_t)ts * 8192;
    dst[(i >> 5) * 2048 + tr * 32 + (i & 31)] = f2b(o1);
    dst[((i + 64) >> 5) * 2048 + tr * 32 + (i & 31)] = f2b(o2);
  } else if (u < 20) {  // K head: rope
    int kvh = u - 16;
    const float* src = QKV + (size_t)t * QKVW_ + NQ_ + kvh * 128;
    float x1 = src[i], x2 = src[i + 64];
    float p = (float)pos[t];
    float f = p * expf(-0.21586735246819178f * (float)i);
    float sn, cs; sincosf(f, &sn, &cs);
    ushort_t* dst = Kbh + (size_t)kvh * (T_ * 128) + (size_t)ts * 8192;
    dst[(i >> 5) * 2048 + tr * 32 + (i & 31)] = f2b(x1 * cs - x2 * sn);
    dst[((i + 64) >> 5) * 2048 + tr * 32 + (i & 31)] = f2b(x2 * cs + x1 * sn);
  } else {  // V head: transpose
    int kvh = u - 20;
    const float* src = QKV + (size_t)t * QKVW_ + NQ_ + NKV_ + kvh * 128;
    float x1 = src[i], x2 = src[i + 64];
    ushort_t* dst = Vth + (size_t)kvh * (T_ * 128) + (size_t)ts * 8192;
    int base = (tr >> 5) * 4096 + (tr & 31);
    dst[base + i * 32] = f2b(x1);
    dst[base + (i + 64) * 32] = f2b(x2);
  }
}

// ---------------- MFMA causal GQA flash attention ----------------
// flat grid 512: (qt, h) with symmetric qt pairing for causal load balance.
// 4 waves; wave w owns q-rows [w*16, w*16+16). 64-key tiles, online softmax.
__global__ __launch_bounds__(256) void attn2_k(const ushort_t* __restrict__ Qbh,
                                               const ushort_t* __restrict__ Kbh,
                                               const ushort_t* __restrict__ Vth,
                                               ushort_t* __restrict__ O) {
  __shared__ __align__(16) ushort_t Qs[8192];  // Q tile; reused as per-wave P
  __shared__ __align__(16) ushort_t Ks[8192];
  __shared__ __align__(16) ushort_t Vs[8192];
  int idx = blockIdx.x;
  int h = idx & 15;
  int qt = (idx < 256) ? (idx >> 4) : (31 - ((idx - 256) >> 4));
  int kvh = h >> 2;
  int q0 = qt * 64;
  int tid = threadIdx.x;
  int w = tid >> 6, lane = tid & 63;
  int m = lane & 15, qd = lane >> 4;
  {
    const ushort_t* qsrc = Qbh + (size_t)h * (T_ * 128) + (size_t)qt * 8192 + w * 2048 + lane * 8;
    ushort_t* qdst = Qs + w * 2048;
#pragma unroll
    for (int i = 0; i < 4; i++) GLD_LDS16(qsrc + i * 512, qdst + i * 512);
  }
  __syncthreads();
  short8 qf[4];
#pragma unroll
  for (int kb = 0; kb < 4; kb++)
    qf[kb] = *(const short8*)&Qs[kb * 2048 + (w * 16 + m) * 32 + qd * 8];
  f4v o4[8] = {};
  float mrow[4], lrow[4];
#pragma unroll
  for (int r = 0; r < 4; r++) { mrow[r] = -INFINITY; lrow[r] = 0.f; }
  ushort_t* Pl = Qs + w * 2048;  // per-wave P strip [16][72] bf16
  const ushort_t* kbase = Kbh + (size_t)kvh * (T_ * 128);
  const ushort_t* vbase = Vth + (size_t)kvh * (T_ * 128);
  int nst = qt + 1;
  for (int st = 0; st < nst; st++) {
    __syncthreads();  // prior-tile LDS reads (and initial qf reads) complete
    {
      const ushort_t* ks = kbase + (size_t)st * 8192 + w * 2048 + lane * 8;
      const ushort_t* vs = vbase + (size_t)st * 8192 + w * 2048 + lane * 8;
      ushort_t* kd = Ks + w * 2048;
      ushort_t* vd = Vs + w * 2048;
#pragma unroll
      for (int i = 0; i < 4; i++) {
        GLD_LDS16(ks + i * 512, kd + i * 512);
        GLD_LDS16(vs + i * 512, vd + i * 512);
      }
    }
    __syncthreads();  // staging landed
    f4v s4[4];
#pragma unroll
    for (int j = 0; j < 4; j++) {
      f4v z = {};
      s4[j] = z;
#pragma unroll
      for (int kb = 0; kb < 4; kb++) {
        short8 kf = *(const short8*)&Ks[kb * 2048 + (j * 16 + m) * 32 + qd * 8];
        s4[j] = __builtin_amdgcn_mfma_f32_16x16x32_bf16(qf[kb], kf, s4[j], 0, 0, 0);
      }
    }
    if (st == nst - 1) {  // diagonal tile
      int s0 = st * 64;
#pragma unroll
      for (int j = 0; j < 4; j++) {
        int col = s0 + j * 16 + m;
#pragma unroll
        for (int r = 0; r < 4; r++) {
          int row = q0 + w * 16 + qd * 4 + r;
          if (col > row) s4[j][r] = -INFINITY;
        }
      }
    }
    float alpha[4];
#pragma unroll
    for (int r = 0; r < 4; r++) {
      float mx = fmaxf(fmaxf(s4[0][r], s4[1][r]), fmaxf(s4[2][r], s4[3][r]));
#pragma unroll
      for (int off = 1; off < 16; off <<= 1) mx = fmaxf(mx, __shfl_xor(mx, off, 64));
      float mn = fmaxf(mrow[r], mx);
      alpha[r] = expf(mrow[r] - mn);
      mrow[r] = mn;
      float ls = 0.f;
#pragma unroll
      for (int j = 0; j < 4; j++) {
        float p = expf(s4[j][r] - mn);
        s4[j][r] = p;
        ls += p;
      }
#pragma unroll
      for (int off = 1; off < 16; off <<= 1) ls += __shfl_xor(ls, off, 64);
      lrow[r] = lrow[r] * alpha[r] + ls;
    }
#pragma unroll
    for (int jd = 0; jd < 8; jd++)
#pragma unroll
      for (int r = 0; r < 4; r++) o4[jd][r] *= alpha[r];
    // P (C-layout) -> per-wave LDS strip, stride 72 (16B-aligned rows)
#pragma unroll
    for (int j = 0; j < 4; j++)
#pragma unroll
      for (int r = 0; r < 4; r++)
        Pl[(qd * 4 + r) * 72 + j * 16 + m] = f2b(s4[j][r]);
    short8 pf[2];
#pragma unroll
    for (int kb2 = 0; kb2 < 2; kb2++)
      pf[kb2] = *(const short8*)&Pl[m * 72 + kb2 * 32 + qd * 8];
#pragma unroll
    for (int jd = 0; jd < 8; jd++)
#pragma unroll
      for (int kb2 = 0; kb2 < 2; kb2++) {
        short8 vf = *(const short8*)&Vs[kb2 * 4096 + (jd * 16 + m) * 32 + qd * 8];
        o4[jd] = __builtin_amdgcn_mfma_f32_16x16x32_bf16(pf[kb2], vf, o4[jd], 0, 0, 0);
      }
  }
  float inv[4];
#pragma unroll
  for (int r = 0; r < 4; r++) inv[r] = 1.0f / lrow[r];
#pragma unroll
  for (int jd = 0; jd < 8; jd++)
#pragma unroll
    for (int r = 0; r < 4; r++) {
      int row = q0 + w * 16 + qd * 4 + r;
      O[(size_t)row * NQ_ + h * 128 + jd * 16 + m] = f2b(o4[jd][r] * inv[r]);
    }
}

// ---------------- router (f32 inputs -> exact top-2 vs reference) ----------------
__global__ __launch_bounds__(256) void router_k(const float* __restrict__ X,
                                                const float* __restrict__ GW,
                                                int* __restrict__ tids,
                                                float* __restrict__ tws) {
  int t = blockIdx.x;
  int tid = threadIdx.x;
  const float* xr = X + (size_t)t * D_ + tid * 8;
  float4 a = *(const float4*)xr;
  float4 b = *(const float4*)(xr + 4);
  float xv[8] = {a.x, a.y, a.z, a.w, b.x, b.y, b.z, b.w};
  float acc[8] = {};
  const float* g = GW + (size_t)tid * 64;
#pragma unroll
  for (int rrow = 0; rrow < 8; rrow++) {
    float4 g0 = *(const float4*)(g + rrow * 8);
    float4 g1 = *(const float4*)(g + rrow * 8 + 4);
    float xs = xv[rrow];
    acc[0] += xs * g0.x; acc[1] += xs * g0.y; acc[2] += xs * g0.z; acc[3] += xs * g0.w;
    acc[4] += xs * g1.x; acc[5] += xs * g1.y; acc[6] += xs * g1.z; acc[7] += xs * g1.w;
  }
#pragma unroll
  for (int e = 0; e < 8; e++)
#pragma unroll
    for (int off = 32; off >= 1; off >>= 1) acc[e] += __shfl_xor(acc[e], off, 64);
  __shared__ float part[4][8];
  if ((tid & 63) == 0)
#pragma unroll
    for (int e = 0; e < 8; e++) part[tid >> 6][e] = acc[e];
  __syncthreads();
  if (tid == 0) {
    float lg[8];
#pragma unroll
    for (int e = 0; e < 8; e++) lg[e] = part[0][e] + part[1][e] + part[2][e] + part[3][e];
    int i1 = 0;
    for (int e = 1; e < 8; e++) if (lg[e] > lg[i1]) i1 = e;
    int i2 = (i1 == 0) ? 1 : 0;
    for (int e = 0; e < 8; e++) if (e != i1 && lg[e] > lg[i2]) i2 = e;
    float e2 = expf(lg[i2] - lg[i1]);
    float s = 1.0f + e2;
    tids[t * 2] = i1; tids[t * 2 + 1] = i2;
    tws[t * 2] = 1.0f / s; tws[t * 2 + 1] = e2 / s;
  }
}

__global__ __launch_bounds__(256) void route_build_k(const int* __restrict__ tids,
                                                     const float* __restrict__ tws,
                                                     int* __restrict__ offs,
                                                     int* __restrict__ ptok,
                                                     float* __restrict__ pw) {
  __shared__ int cnt[8];
  __shared__ int cur[8];
  int tid = threadIdx.x;
  if (tid < 8) cnt[tid] = 0;
  __syncthreads();
  for (int s = tid; s < T_ * 2; s += 256) atomicAdd(&cnt[tids[s]], 1);
  __syncthreads();
  if (tid == 0) {
    int o = 0;
    for (int e = 0; e < 8; e++) { cur[e] = o; offs[e] = o; o += cnt[e]; }
    offs[8] = o;
  }
  __syncthreads();
  for (int s = tid; s < T_ * 2; s += 256) {
    int e = tids[s];
    int p = atomicAdd(&cur[e], 1);
    ptok[p] = s >> 1;
    pw[p] = tws[s];
  }
}

// ---------------- SwiGLU: FF = silu(G) * U (bf16) ----------------
__global__ __launch_bounds__(256) void swiglu_k(const ushort_t* __restrict__ G,
                                                const ushort_t* __restrict__ U,
                                                ushort_t* __restrict__ FF) {
  int i = (blockIdx.x * 256 + threadIdx.x) * 4;
  ushort4 g4 = *(const ushort4*)&G[i];
  ushort4 u4 = *(const ushort4*)&U[i];
  float g[4] = {b2f(g4.x), b2f(g4.y), b2f(g4.z), b2f(g4.w)};
  float u[4] = {b2f(u4.x), b2f(u4.y), b2f(u4.z), b2f(u4.w)};
  ushort4 o;
  o.x = f2b(g[0] / (1.f + expf(-g[0])) * u[0]);
  o.y = f2b(g[1] / (1.f + expf(-g[1])) * u[1]);
  o.z = f2b(g[2] / (1.f + expf(-g[2])) * u[2]);
  o.w = f2b(g[3] / (1.f + expf(-g[3])) * u[3]);
  *(ushort4*)&FF[i] = o;
}

extern "C" void kernel_launch(void* const* d_in, const int* in_sizes, int n_in,
                              void* d_out, int out_size, void* d_ws, size_t ws_size,
                              hipStream_t stream) {
  const float* hs  = (const float*)d_in[0];
  const int*   pos = (const int*)d_in[1];
  const float* ln1 = (const float*)d_in[2];
  const float* ln2 = (const float*)d_in[3];
  const float* wq  = (const float*)d_in[4];
  const float* bq  = (const float*)d_in[5];
  const float* wk  = (const float*)d_in[6];
  const float* bk  = (const float*)d_in[7];
  const float* wv  = (const float*)d_in[8];
  const float* bvp = (const float*)d_in[9];
  const float* wo  = (const float*)d_in[10];
  const float* gw  = (const float*)d_in[11];
  const float* wg  = (const float*)d_in[12];
  const float* wu  = (const float*)d_in[13];
  const float* wd  = (const float*)d_in[14];
  float* out = (float*)d_out;

  const size_t M = 1048576;
  float* ws = (float*)d_ws;
  // [0,4M) floats: attention buffers (Qbh/Kbh/Vth), then reused as XN f32
  ushort_t* Qbh   = (ushort_t*)ws;                  // 4M bf16 [0,2M)
  ushort_t* Kbh   = (ushort_t*)(ws + 2 * M);        // 1M bf16 [2M,2.5M)
  ushort_t* Vth   = (ushort_t*)(ws + 2621440);      // 1M bf16 [2.5M,3M)
  float*    XN    = ws;                             // 4M f32 (post-attention)
  float*    QKV   = ws + 4 * M;                     // 6M f32 (later G region)
  ushort_t* G     = (ushort_t*)QKV;                 // 4M bf16
  ushort_t* U     = (ushort_t*)(ws + 6 * M);        // 4M bf16
  ushort_t* XNb   = (ushort_t*)(ws + 10 * M);       // 4M bf16
  ushort_t* ATb   = (ushort_t*)(ws + 12 * M);       // 4M bf16 (reused as FF)
  ushort_t* FF    = ATb;
  ushort_t* wqkvT = (ushort_t*)(ws + 14 * M);       // 3072x2048 bf16
  ushort_t* woT   = (ushort_t*)(ws + 17 * M);       // 2048x2048 bf16
  ushort_t* wgT   = (ushort_t*)(ws + 19 * M);       // 8x1024x2048 bf16
  ushort_t* wuT   = (ushort_t*)(ws + 27 * M);       // 8x1024x2048 bf16
  ushort_t* wdT   = (ushort_t*)(ws + 35 * M);       // 8x2048x1024 bf16
  float*    biasC = ws + 43 * M;                    // 3072 f32
  int*      tids  = (int*)(biasC + 4096);
  float*    tws   = (float*)(tids + 4096);
  int*      offs  = (int*)(tws + 4096);
  int*      ptok  = offs + 16;
  float*    pw    = (float*)(ptok + 4096);

  // ---- weight pre-pass: transpose + bf16 convert ----
  tcvt_k<<<dim3(64, 64, 1), 256, 0, stream>>>(wq, wqkvT, 2048, 2048, 0, 0);
  tcvt_k<<<dim3(16, 64, 1), 256, 0, stream>>>(wk, wqkvT + (size_t)2048 * 2048, 2048, 512, 0, 0);
  tcvt_k<<<dim3(16, 64, 1), 256, 0, stream>>>(wv, wqkvT + (size_t)2560 * 2048, 2048, 512, 0, 0);
  tcvt_k<<<dim3(64, 64, 1), 256, 0, stream>>>(wo, woT, 2048, 2048, 0, 0);
  tcvt_k<<<dim3(32, 64, 8), 256, 0, stream>>>(wg, wgT, 2048, 1024, 2048L * 1024, 2048L * 1024);
  tcvt_k<<<dim3(32, 64, 8), 256, 0, stream>>>(wu, wuT, 2048, 1024, 2048L * 1024, 2048L * 1024);
  tcvt_k<<<dim3(64, 32, 8), 256, 0, stream>>>(wd, wdT, 1024, 2048, 1024L * 2048, 1024L * 2048);
  bias_concat_k<<<12, 256, 0, stream>>>(bq, bk, bvp, biasC);

  // ---- layer ----
  rmsnorm_k<<<T_, 256, 0, stream>>>(hs, ln1, nullptr, XNb);
  gemm_bf16_k<0, false, false><<<dim3(16, 24, 1), 256, 0, stream>>>(
      XNb, wqkvT, nullptr, D_, QKVW_, 0, QKV, nullptr, nullptr, biasC, nullptr, nullptr);
  qkv_prep_k<<<dim3(T_, 6), 256, 0, stream>>>(QKV, pos, Qbh, Kbh, Vth);
  attn2_k<<<512, 256, 0, stream>>>(Qbh, Kbh, Vth, ATb);
  gemm_bf16_k<1, false, false><<<dim3(16, 16, 1), 256, 0, stream>>>(
      ATb, woT, nullptr, NQ_, D_, 0, out, nullptr, nullptr, hs, nullptr, nullptr);
  rmsnorm_k<<<T_, 256, 0, stream>>>(out, ln2, XN, XNb);
  router_k<<<T_, 256, 0, stream>>>(XN, gw, tids, tws);
  route_build_k<<<1, 256, 0, stream>>>(tids, tws, offs, ptok, pw);
  gemm_bf16_k<2, true, true><<<dim3(32, 16, 8), 256, 0, stream>>>(
      XNb, wgT, wuT, D_, I_, 1024L * 2048, nullptr, G, U, nullptr, offs, ptok);
  swiglu_k<<<4096, 256, 0, stream>>>(G, U, FF);
  gemm_bf16_k<3, false, false><<<dim3(32, 16, 8), 256, 0, stream>>>(
      FF, wdT, nullptr, I_, D_, 1024L * 2048, out, nullptr, nullptr, pw, offs, ptok);
}

// Round 4
// 810.862 us; speedup vs baseline: 4.6684x; 1.3592x over previous
//
#include <hip/hip_runtime.h>
#include <math.h>

#define T_ 2048
#define D_ 2048
#define H_ 16
#define KVH_ 4
#define HD_ 128
#define E_ 8
#define I_ 1024
#define NQ_ 2048   // H_*HD_
#define NKV_ 512   // KVH_*HD_
#define QKVW_ 3072 // NQ_ + 2*NKV_

typedef unsigned short ushort_t;
typedef unsigned int uint_t;
typedef __attribute__((ext_vector_type(8))) short short8;
typedef __attribute__((ext_vector_type(4))) float f4v;

__device__ __forceinline__ ushort_t f2b(float x) {
  union { float f; uint_t u; } v; v.f = x;
  uint_t r = v.u + 0x7FFFu + ((v.u >> 16) & 1u);
  return (ushort_t)(r >> 16);
}
__device__ __forceinline__ float b2f(ushort_t b) {
  union { uint_t u; float f; } v; v.u = ((uint_t)b) << 16;
  return v.f;
}

#define GLD_LDS16(gp, lp)                                                      \
  __builtin_amdgcn_global_load_lds(                                            \
      (const __attribute__((address_space(1))) uint_t*)(gp),                   \
      (__attribute__((address_space(3))) uint_t*)(lp), 16, 0, 0)

// ---------------- transpose + f32->bf16 convert: out[C x R] = in[R x C]^T ----
__global__ __launch_bounds__(256) void tcvt_k(const float* __restrict__ in,
                                              ushort_t* __restrict__ out,
                                              int R, int C, long inB, long outB) {
  in += (size_t)blockIdx.z * inB;
  out += (size_t)blockIdx.z * outB;
  __shared__ float tile[32][33];
  int r0 = blockIdx.y * 32, c0 = blockIdx.x * 32;
  int tr = threadIdx.x >> 3, tc = (threadIdx.x & 7) * 4;
  float4 v = *(const float4*)&in[(size_t)(r0 + tr) * C + c0 + tc];
  tile[tr][tc] = v.x; tile[tr][tc + 1] = v.y;
  tile[tr][tc + 2] = v.z; tile[tr][tc + 3] = v.w;
  __syncthreads();
  ushort4 o;
  o.x = f2b(tile[tc + 0][tr]); o.y = f2b(tile[tc + 1][tr]);
  o.z = f2b(tile[tc + 2][tr]); o.w = f2b(tile[tc + 3][tr]);
  *(ushort4*)&out[(size_t)(c0 + tr) * R + r0 + tc] = o;
}

// ---------------- bias concat [bq | bk | bv] -> 3072 ----------------
__global__ __launch_bounds__(256) void bias_concat_k(const float* __restrict__ bq,
                                                     const float* __restrict__ bk,
                                                     const float* __restrict__ bv,
                                                     float* __restrict__ bc) {
  int i = blockIdx.x * 256 + threadIdx.x;
  bc[i] = i < NQ_ ? bq[i] : (i < NQ_ + NKV_ ? bk[i - NQ_] : bv[i - NQ_ - NKV_]);
}

// ---------------- RMSNorm 1: bf16 out ----------------
__global__ __launch_bounds__(256) void rmsnorm_k(const float* __restrict__ x,
                                                 const float* __restrict__ w,
                                                 ushort_t* __restrict__ yb) {
  int t = blockIdx.x;
  int tid = threadIdx.x;
  const float* xr = x + (size_t)t * D_;
  float4 a = *(const float4*)&xr[tid * 8];
  float4 b = *(const float4*)&xr[tid * 8 + 4];
  float v[8] = {a.x, a.y, a.z, a.w, b.x, b.y, b.z, b.w};
  float ss = 0.f;
#pragma unroll
  for (int i = 0; i < 8; i++) ss += v[i] * v[i];
#pragma unroll
  for (int off = 32; off >= 1; off >>= 1) ss += __shfl_xor(ss, off, 64);
  __shared__ float part[4];
  __shared__ float scsh;
  if ((tid & 63) == 0) part[tid >> 6] = ss;
  __syncthreads();
  if (tid == 0) scsh = rsqrtf((part[0] + part[1] + part[2] + part[3]) * (1.0f / D_) + 1e-6f);
  __syncthreads();
  float sc = scsh;
  float4 w0 = *(const float4*)&w[tid * 8];
  float4 w1 = *(const float4*)&w[tid * 8 + 4];
  float wv[8] = {w0.x, w0.y, w0.z, w0.w, w1.x, w1.y, w1.z, w1.w};
  ushort_t* ybr = yb + (size_t)t * D_;
  ushort4 p0, p1;
  p0.x = f2b(v[0] * sc * wv[0]); p0.y = f2b(v[1] * sc * wv[1]);
  p0.z = f2b(v[2] * sc * wv[2]); p0.w = f2b(v[3] * sc * wv[3]);
  p1.x = f2b(v[4] * sc * wv[4]); p1.y = f2b(v[5] * sc * wv[5]);
  p1.z = f2b(v[6] * sc * wv[6]); p1.w = f2b(v[7] * sc * wv[7]);
  *(ushort4*)&ybr[tid * 8] = p0;
  *(ushort4*)&ybr[tid * 8 + 4] = p1;
}

// ---------------- RMSNorm 2 + O-proj partial combine + residual ----------------
// h = hs + Op0 + Op1 -> out (f32); rmsnorm(h) -> XN (f32) + XNb (bf16)
__global__ __launch_bounds__(256) void rms2_comb_k(const float* __restrict__ hs,
                                                   const ushort_t* __restrict__ Op0,
                                                   const ushort_t* __restrict__ Op1,
                                                   const float* __restrict__ w,
                                                   float* __restrict__ outh,
                                                   float* __restrict__ XN,
                                                   ushort_t* __restrict__ XNb) {
  int t = blockIdx.x;
  int tid = threadIdx.x;
  size_t base = (size_t)t * D_ + tid * 8;
  float4 a = *(const float4*)&hs[base];
  float4 b = *(const float4*)&hs[base + 4];
  ushort4 o00 = *(const ushort4*)&Op0[base];
  ushort4 o01 = *(const ushort4*)&Op0[base + 4];
  ushort4 o10 = *(const ushort4*)&Op1[base];
  ushort4 o11 = *(const ushort4*)&Op1[base + 4];
  float v[8];
  v[0] = a.x + b2f(o00.x) + b2f(o10.x);
  v[1] = a.y + b2f(o00.y) + b2f(o10.y);
  v[2] = a.z + b2f(o00.z) + b2f(o10.z);
  v[3] = a.w + b2f(o00.w) + b2f(o10.w);
  v[4] = b.x + b2f(o01.x) + b2f(o11.x);
  v[5] = b.y + b2f(o01.y) + b2f(o11.y);
  v[6] = b.z + b2f(o01.z) + b2f(o11.z);
  v[7] = b.w + b2f(o01.w) + b2f(o11.w);
  *(float4*)&outh[base] = make_float4(v[0], v[1], v[2], v[3]);
  *(float4*)&outh[base + 4] = make_float4(v[4], v[5], v[6], v[7]);
  float ss = 0.f;
#pragma unroll
  for (int i = 0; i < 8; i++) ss += v[i] * v[i];
#pragma unroll
  for (int off = 32; off >= 1; off >>= 1) ss += __shfl_xor(ss, off, 64);
  __shared__ float part[4];
  __shared__ float scsh;
  if ((tid & 63) == 0) part[tid >> 6] = ss;
  __syncthreads();
  if (tid == 0) scsh = rsqrtf((part[0] + part[1] + part[2] + part[3]) * (1.0f / D_) + 1e-6f);
  __syncthreads();
  float sc = scsh;
  float4 w0 = *(const float4*)&w[tid * 8];
  float4 w1 = *(const float4*)&w[tid * 8 + 4];
  float wv[8] = {w0.x, w0.y, w0.z, w0.w, w1.x, w1.y, w1.z, w1.w};
  float o[8];
#pragma unroll
  for (int i = 0; i < 8; i++) o[i] = v[i] * sc * wv[i];
  *(float4*)&XN[base] = make_float4(o[0], o[1], o[2], o[3]);
  *(float4*)&XN[base + 4] = make_float4(o[4], o[5], o[6], o[7]);
  ushort4 p0, p1;
  p0.x = f2b(o[0]); p0.y = f2b(o[1]); p0.z = f2b(o[2]); p0.w = f2b(o[3]);
  p1.x = f2b(o[4]); p1.y = f2b(o[5]); p1.z = f2b(o[6]); p1.w = f2b(o[7]);
  *(ushort4*)&XNb[base] = p0;
  *(ushort4*)&XNb[base + 4] = p1;
}

// ---------------- uniform bf16 MFMA GEMM, split-K x2, bf16 partial stores ----
// 128x128 tile, BK=32, 4 waves (each 64x64 of 16x16x32 MFMA).
// blockIdx.x = (m << 1) | ks.  A row-major [rows x Kd], BT row-major [N x Kd].
// Partial ks writes bf16 to Ob + ks*partStride at [row x N].
// ROUTED: rows are expert-compacted slots via offs[e]; A is slot-indexed
// (pre-gathered); stores masked to slot < end.
template <bool ROUTED, bool DUAL>
__global__ __launch_bounds__(256) void gemm2_k(
    const ushort_t* __restrict__ A, const ushort_t* __restrict__ BT0,
    const ushort_t* __restrict__ BT1, int Kd, int kLen, int N, long bExpStride,
    ushort_t* __restrict__ Ob0, ushort_t* __restrict__ Ob1, long partStride,
    const int* __restrict__ offs) {
  int e = blockIdx.z;
  int bx = blockIdx.x;
  int ks = bx & 1;
  int m0 = (bx >> 1) * 128;
  int ny = blockIdx.y;
  const ushort_t* BT = BT0;
  ushort_t* Ob = Ob0;
  if (DUAL) {
    int half = gridDim.y >> 1;
    if (ny >= half) { ny -= half; BT = BT1; Ob = Ob1; }
  }
  int n0 = ny * 128;
  int off = 0, end = 0x7fffffff;
  if (ROUTED) {
    off = offs[e];
    end = offs[e + 1];
    if (off + m0 >= end) return;
    BT += (size_t)e * bExpStride;
  }
  Ob += (size_t)ks * partStride;
  int kOff = ks * kLen;
  __shared__ __align__(16) ushort_t As[128 * 32];
  __shared__ __align__(16) ushort_t Bs[128 * 32];
  int tid = threadIdx.x;
  int lane = tid & 63, w = tid >> 6;
  int r1 = tid >> 2, kc = (tid & 3) << 3;
  int s1 = off + m0 + r1, s2 = s1 + 64;
  if (ROUTED) {
    if (s1 > end - 1) s1 = end - 1;
    if (s2 > end - 1) s2 = end - 1;
  }
  const ushort_t* gA1 = A + (size_t)s1 * Kd + kOff + kc;
  const ushort_t* gA2 = A + (size_t)s2 * Kd + kOff + kc;
  const ushort_t* gB1 = BT + (size_t)(n0 + r1) * Kd + kOff + kc;
  const ushort_t* gB2 = gB1 + (size_t)64 * Kd;
  ushort_t* lA = As + (tid & 192) * 8;
  ushort_t* lB = Bs + (tid & 192) * 8;
  f4v acc[4][4] = {};
  int ml = lane & 15, q = lane >> 4;
  int wm = (w & 1) << 6, wn = (w >> 1) << 6;
  for (int k0 = 0; k0 < kLen; k0 += 32) {
    GLD_LDS16(gA1 + k0, lA);
    GLD_LDS16(gA2 + k0, lA + 2048);
    GLD_LDS16(gB1 + k0, lB);
    GLD_LDS16(gB2 + k0, lB + 2048);
    __syncthreads();
    short8 af[4], bf[4];
#pragma unroll
    for (int i = 0; i < 4; i++)
      af[i] = *(const short8*)&As[(wm + i * 16 + ml) * 32 + q * 8];
#pragma unroll
    for (int j = 0; j < 4; j++)
      bf[j] = *(const short8*)&Bs[(wn + j * 16 + ml) * 32 + q * 8];
#pragma unroll
    for (int i = 0; i < 4; i++)
#pragma unroll
      for (int j = 0; j < 4; j++)
        acc[i][j] = __builtin_amdgcn_mfma_f32_16x16x32_bf16(af[i], bf[j], acc[i][j], 0, 0, 0);
    __syncthreads();
  }
#pragma unroll
  for (int i = 0; i < 4; i++) {
#pragma unroll
    for (int r = 0; r < 4; r++) {
      int row = off + m0 + wm + i * 16 + q * 4 + r;
      if (ROUTED && row >= end) continue;
      size_t base = (size_t)row * N + n0 + wn + ml;
#pragma unroll
      for (int j = 0; j < 4; j++) Ob[base + j * 16] = f2b(acc[i][j][r]);
    }
  }
}

// ---------------- QKV prep: partial sum + bias + RoPE + chunked layouts ----
// Qbh: [H][T/64][kb=4][64][32] (scaled); Kbh: [KVH][T/64][4][64][32];
// Vth: [KVH][T/64][kb2=2][128][32]  (V transposed: element (d, t)).
__global__ __launch_bounds__(256) void qkv_prep_k(const ushort_t* __restrict__ P0,
                                                  const ushort_t* __restrict__ P1,
                                                  const float* __restrict__ biasC,
                                                  const int* __restrict__ pos,
                                                  ushort_t* __restrict__ Qbh,
                                                  ushort_t* __restrict__ Kbh,
                                                  ushort_t* __restrict__ Vth) {
  int t = blockIdx.x;
  int u = blockIdx.y * 4 + (threadIdx.x >> 6);
  int i = threadIdx.x & 63;
  int ts = t >> 6, tr = t & 63;
  const float scale = 0.08838834764831845f;
  size_t rowb = (size_t)t * QKVW_;
  if (u < 16) {  // Q head u: rope + scale
    int c1 = u * 128 + i, c2 = c1 + 64;
    float x1 = b2f(P0[rowb + c1]) + b2f(P1[rowb + c1]) + biasC[c1];
    float x2 = b2f(P0[rowb + c2]) + b2f(P1[rowb + c2]) + biasC[c2];
    float p = (float)pos[t];
    float f = p * expf(-0.21586735246819178f * (float)i);
    float sn, cs; sincosf(f, &sn, &cs);
    float o1 = (x1 * cs - x2 * sn) * scale;
    float o2 = (x2 * cs + x1 * sn) * scale;
    ushort_t* dst = Qbh + (size_t)u * (T_ * 128) + (size_t)ts * 8192;
    dst[(i >> 5) * 2048 + tr * 32 + (i & 31)] = f2b(o1);
    dst[((i + 64) >> 5) * 2048 + tr * 32 + (i & 31)] = f2b(o2);
  } else if (u < 20) {  // K head: rope
    int kvh = u - 16;
    int c1 = NQ_ + kvh * 128 + i, c2 = c1 + 64;
    float x1 = b2f(P0[rowb + c1]) + b2f(P1[rowb + c1]) + biasC[c1];
    float x2 = b2f(P0[rowb + c2]) + b2f(P1[rowb + c2]) + biasC[c2];
    float p = (float)pos[t];
    float f = p * expf(-0.21586735246819178f * (float)i);
    float sn, cs; sincosf(f, &sn, &cs);
    ushort_t* dst = Kbh + (size_t)kvh * (T_ * 128) + (size_t)ts * 8192;
    dst[(i >> 5) * 2048 + tr * 32 + (i & 31)] = f2b(x1 * cs - x2 * sn);
    dst[((i + 64) >> 5) * 2048 + tr * 32 + (i & 31)] = f2b(x2 * cs + x1 * sn);
  } else {  // V head: transpose
    int kvh = u - 20;
    int c1 = NQ_ + NKV_ + kvh * 128 + i, c2 = c1 + 64;
    float x1 = b2f(P0[rowb + c1]) + b2f(P1[rowb + c1]) + biasC[c1];
    float x2 = b2f(P0[rowb + c2]) + b2f(P1[rowb + c2]) + biasC[c2];
    ushort_t* dst = Vth + (size_t)kvh * (T_ * 128) + (size_t)ts * 8192;
    int base = (tr >> 5) * 4096 + (tr & 31);
    dst[base + i * 32] = f2b(x1);
    dst[base + (i + 64) * 32] = f2b(x2);
  }
}

// ---------------- MFMA causal GQA flash attention ----------------
__global__ __launch_bounds__(256) void attn2_k(const ushort_t* __restrict__ Qbh,
                                               const ushort_t* __restrict__ Kbh,
                                               const ushort_t* __restrict__ Vth,
                                               ushort_t* __restrict__ O) {
  __shared__ __align__(16) ushort_t Qs[8192];  // Q tile; reused as per-wave P
  __shared__ __align__(16) ushort_t Ks[8192];
  __shared__ __align__(16) ushort_t Vs[8192];
  int idx = blockIdx.x;
  int h = idx & 15;
  int qt = (idx < 256) ? (idx >> 4) : (31 - ((idx - 256) >> 4));
  int kvh = h >> 2;
  int q0 = qt * 64;
  int tid = threadIdx.x;
  int w = tid >> 6, lane = tid & 63;
  int m = lane & 15, qd = lane >> 4;
  {
    const ushort_t* qsrc = Qbh + (size_t)h * (T_ * 128) + (size_t)qt * 8192 + w * 2048 + lane * 8;
    ushort_t* qdst = Qs + w * 2048;
#pragma unroll
    for (int i = 0; i < 4; i++) GLD_LDS16(qsrc + i * 512, qdst + i * 512);
  }
  __syncthreads();
  short8 qf[4];
#pragma unroll
  for (int kb = 0; kb < 4; kb++)
    qf[kb] = *(const short8*)&Qs[kb * 2048 + (w * 16 + m) * 32 + qd * 8];
  f4v o4[8] = {};
  float mrow[4], lrow[4];
#pragma unroll
  for (int r = 0; r < 4; r++) { mrow[r] = -INFINITY; lrow[r] = 0.f; }
  ushort_t* Pl = Qs + w * 2048;  // per-wave P strip [16][72] bf16
  const ushort_t* kbase = Kbh + (size_t)kvh * (T_ * 128);
  const ushort_t* vbase = Vth + (size_t)kvh * (T_ * 128);
  int nst = qt + 1;
  for (int st = 0; st < nst; st++) {
    __syncthreads();
    {
      const ushort_t* ks = kbase + (size_t)st * 8192 + w * 2048 + lane * 8;
      const ushort_t* vs = vbase + (size_t)st * 8192 + w * 2048 + lane * 8;
      ushort_t* kd = Ks + w * 2048;
      ushort_t* vd = Vs + w * 2048;
#pragma unroll
      for (int i = 0; i < 4; i++) {
        GLD_LDS16(ks + i * 512, kd + i * 512);
        GLD_LDS16(vs + i * 512, vd + i * 512);
      }
    }
    __syncthreads();
    f4v s4[4];
#pragma unroll
    for (int j = 0; j < 4; j++) {
      f4v z = {};
      s4[j] = z;
#pragma unroll
      for (int kb = 0; kb < 4; kb++) {
        short8 kf = *(const short8*)&Ks[kb * 2048 + (j * 16 + m) * 32 + qd * 8];
        s4[j] = __builtin_amdgcn_mfma_f32_16x16x32_bf16(qf[kb], kf, s4[j], 0, 0, 0);
      }
    }
    if (st == nst - 1) {
      int s0 = st * 64;
#pragma unroll
      for (int j = 0; j < 4; j++) {
        int col = s0 + j * 16 + m;
#pragma unroll
        for (int r = 0; r < 4; r++) {
          int row = q0 + w * 16 + qd * 4 + r;
          if (col > row) s4[j][r] = -INFINITY;
        }
      }
    }
    float alpha[4];
#pragma unroll
    for (int r = 0; r < 4; r++) {
      float mx = fmaxf(fmaxf(s4[0][r], s4[1][r]), fmaxf(s4[2][r], s4[3][r]));
#pragma unroll
      for (int off = 1; off < 16; off <<= 1) mx = fmaxf(mx, __shfl_xor(mx, off, 64));
      float mn = fmaxf(mrow[r], mx);
      alpha[r] = expf(mrow[r] - mn);
      mrow[r] = mn;
      float ls = 0.f;
#pragma unroll
      for (int j = 0; j < 4; j++) {
        float p = expf(s4[j][r] - mn);
        s4[j][r] = p;
        ls += p;
      }
#pragma unroll
      for (int off = 1; off < 16; off <<= 1) ls += __shfl_xor(ls, off, 64);
      lrow[r] = lrow[r] * alpha[r] + ls;
    }
#pragma unroll
    for (int jd = 0; jd < 8; jd++)
#pragma unroll
      for (int r = 0; r < 4; r++) o4[jd][r] *= alpha[r];
#pragma unroll
    for (int j = 0; j < 4; j++)
#pragma unroll
      for (int r = 0; r < 4; r++)
        Pl[(qd * 4 + r) * 72 + j * 16 + m] = f2b(s4[j][r]);
    short8 pf[2];
#pragma unroll
    for (int kb2 = 0; kb2 < 2; kb2++)
      pf[kb2] = *(const short8*)&Pl[m * 72 + kb2 * 32 + qd * 8];
#pragma unroll
    for (int jd = 0; jd < 8; jd++)
#pragma unroll
      for (int kb2 = 0; kb2 < 2; kb2++) {
        short8 vf = *(const short8*)&Vs[kb2 * 4096 + (jd * 16 + m) * 32 + qd * 8];
        o4[jd] = __builtin_amdgcn_mfma_f32_16x16x32_bf16(pf[kb2], vf, o4[jd], 0, 0, 0);
      }
  }
  float inv[4];
#pragma unroll
  for (int r = 0; r < 4; r++) inv[r] = 1.0f / lrow[r];
#pragma unroll
  for (int jd = 0; jd < 8; jd++)
#pragma unroll
    for (int r = 0; r < 4; r++) {
      int row = q0 + w * 16 + qd * 4 + r;
      O[(size_t)row * NQ_ + h * 128 + jd * 16 + m] = f2b(o4[jd][r] * inv[r]);
    }
}

// ---------------- router (f32 inputs -> exact top-2 vs reference) ----------------
__global__ __launch_bounds__(256) void router_k(const float* __restrict__ X,
                                                const float* __restrict__ GW,
                                                int* __restrict__ tids,
                                                float* __restrict__ tws) {
  int t = blockIdx.x;
  int tid = threadIdx.x;
  const float* xr = X + (size_t)t * D_ + tid * 8;
  float4 a = *(const float4*)xr;
  float4 b = *(const float4*)(xr + 4);
  float xv[8] = {a.x, a.y, a.z, a.w, b.x, b.y, b.z, b.w};
  float acc[8] = {};
  const float* g = GW + (size_t)tid * 64;
#pragma unroll
  for (int rrow = 0; rrow < 8; rrow++) {
    float4 g0 = *(const float4*)(g + rrow * 8);
    float4 g1 = *(const float4*)(g + rrow * 8 + 4);
    float xs = xv[rrow];
    acc[0] += xs * g0.x; acc[1] += xs * g0.y; acc[2] += xs * g0.z; acc[3] += xs * g0.w;
    acc[4] += xs * g1.x; acc[5] += xs * g1.y; acc[6] += xs * g1.z; acc[7] += xs * g1.w;
  }
#pragma unroll
  for (int e = 0; e < 8; e++)
#pragma unroll
    for (int off = 32; off >= 1; off >>= 1) acc[e] += __shfl_xor(acc[e], off, 64);
  __shared__ float part[4][8];
  if ((tid & 63) == 0)
#pragma unroll
    for (int e = 0; e < 8; e++) part[tid >> 6][e] = acc[e];
  __syncthreads();
  if (tid == 0) {
    float lg[8];
#pragma unroll
    for (int e = 0; e < 8; e++) lg[e] = part[0][e] + part[1][e] + part[2][e] + part[3][e];
    int i1 = 0;
    for (int e = 1; e < 8; e++) if (lg[e] > lg[i1]) i1 = e;
    int i2 = (i1 == 0) ? 1 : 0;
    for (int e = 0; e < 8; e++) if (e != i1 && lg[e] > lg[i2]) i2 = e;
    float e2 = expf(lg[i2] - lg[i1]);
    float s = 1.0f + e2;
    tids[t * 2] = i1; tids[t * 2 + 1] = i2;
    tws[t * 2] = 1.0f / s; tws[t * 2 + 1] = e2 / s;
  }
}

// ---------------- per-expert compacted slot lists + inverse map ----------------
__global__ __launch_bounds__(256) void route_build_k(const int* __restrict__ tids,
                                                     int* __restrict__ offs,
                                                     int* __restrict__ ptok,
                                                     int* __restrict__ sidx) {
  __shared__ int cnt[8];
  __shared__ int cur[8];
  int tid = threadIdx.x;
  if (tid < 8) cnt[tid] = 0;
  __syncthreads();
  for (int s = tid; s < T_ * 2; s += 256) atomicAdd(&cnt[tids[s]], 1);
  __syncthreads();
  if (tid == 0) {
    int o = 0;
    for (int e = 0; e < 8; e++) { cur[e] = o; offs[e] = o; o += cnt[e]; }
    offs[8] = o;
  }
  __syncthreads();
  for (int s = tid; s < T_ * 2; s += 256) {
    int e = tids[s];
    int p = atomicAdd(&cur[e], 1);
    ptok[p] = s >> 1;
    sidx[s] = p;
  }
}

// ---------------- gather normed activations into slot order ----------------
__global__ __launch_bounds__(256) void gather_k(const ushort_t* __restrict__ XNb,
                                                const int* __restrict__ ptok,
                                                ushort_t* __restrict__ Ag) {
  int slot = blockIdx.x;
  int tok = ptok[slot];
  const ushort_t* src = XNb + (size_t)tok * D_ + threadIdx.x * 8;
  ushort_t* dst = Ag + (size_t)slot * D_ + threadIdx.x * 8;
  ushort4 a = *(const ushort4*)src;
  ushort4 b = *(const ushort4*)(src + 4);
  *(ushort4*)dst = a;
  *(ushort4*)(dst + 4) = b;
}

// ---------------- SwiGLU over partial pairs: FF = silu(G0+G1) * (U0+U1) ----
__global__ __launch_bounds__(256) void swiglu_k(const ushort_t* __restrict__ Gp,
                                                const ushort_t* __restrict__ Up,
                                                ushort_t* __restrict__ FF) {
  const long PS = 4194304;  // 4096*1024
  long i = (long)(blockIdx.x * 256 + threadIdx.x) * 4;
  ushort4 g0 = *(const ushort4*)&Gp[i];
  ushort4 g1 = *(const ushort4*)&Gp[i + PS];
  ushort4 u0 = *(const ushort4*)&Up[i];
  ushort4 u1 = *(const ushort4*)&Up[i + PS];
  float g[4] = {b2f(g0.x) + b2f(g1.x), b2f(g0.y) + b2f(g1.y),
                b2f(g0.z) + b2f(g1.z), b2f(g0.w) + b2f(g1.w)};
  float u[4] = {b2f(u0.x) + b2f(u1.x), b2f(u0.y) + b2f(u1.y),
                b2f(u0.z) + b2f(u1.z), b2f(u0.w) + b2f(u1.w)};
  ushort4 o;
  o.x = f2b(g[0] / (1.f + expf(-g[0])) * u[0]);
  o.y = f2b(g[1] / (1.f + expf(-g[1])) * u[1]);
  o.z = f2b(g[2] / (1.f + expf(-g[2])) * u[2]);
  o.w = f2b(g[3] / (1.f + expf(-g[3])) * u[3]);
  *(ushort4*)&FF[i] = o;
}

// ---------------- MoE combine: out[t] += w0*Y[s0] + w1*Y[s1] (partial pairs) ----
__global__ __launch_bounds__(256) void moe_combine_k(const ushort_t* __restrict__ Yp,
                                                     const int* __restrict__ sidx,
                                                     const float* __restrict__ tws,
                                                     float* __restrict__ out) {
  const long PS = 8388608;  // 4096*2048
  int t = blockIdx.x;
  int s0 = sidx[t * 2], s1 = sidx[t * 2 + 1];
  float w0 = tws[t * 2], w1 = tws[t * 2 + 1];
  int c = threadIdx.x * 8;
  size_t ob = (size_t)t * D_ + c;
  const ushort_t* y00 = Yp + (size_t)s0 * D_ + c;
  const ushort_t* y10 = Yp + (size_t)s1 * D_ + c;
  float4 r0 = *(const float4*)&out[ob];
  float4 r1 = *(const float4*)&out[ob + 4];
  float acc[8] = {r0.x, r0.y, r0.z, r0.w, r1.x, r1.y, r1.z, r1.w};
  ushort4 a0 = *(const ushort4*)y00;
  ushort4 a1 = *(const ushort4*)(y00 + 4);
  ushort4 b0 = *(const ushort4*)(y00 + PS);
  ushort4 b1 = *(const ushort4*)(y00 + PS + 4);
  acc[0] += w0 * (b2f(a0.x) + b2f(b0.x)); acc[1] += w0 * (b2f(a0.y) + b2f(b0.y));
  acc[2] += w0 * (b2f(a0.z) + b2f(b0.z)); acc[3] += w0 * (b2f(a0.w) + b2f(b0.w));
  acc[4] += w0 * (b2f(a1.x) + b2f(b1.x)); acc[5] += w0 * (b2f(a1.y) + b2f(b1.y));
  acc[6] += w0 * (b2f(a1.z) + b2f(b1.z)); acc[7] += w0 * (b2f(a1.w) + b2f(b1.w));
  a0 = *(const ushort4*)y10;
  a1 = *(const ushort4*)(y10 + 4);
  b0 = *(const ushort4*)(y10 + PS);
  b1 = *(const ushort4*)(y10 + PS + 4);
  acc[0] += w1 * (b2f(a0.x) + b2f(b0.x)); acc[1] += w1 * (b2f(a0.y) + b2f(b0.y));
  acc[2] += w1 * (b2f(a0.z) + b2f(b0.z)); acc[3] += w1 * (b2f(a0.w) + b2f(b0.w));
  acc[4] += w1 * (b2f(a1.x) + b2f(b1.x)); acc[5] += w1 * (b2f(a1.y) + b2f(b1.y));
  acc[6] += w1 * (b2f(a1.z) + b2f(b1.z)); acc[7] += w1 * (b2f(a1.w) + b2f(b1.w));
  *(float4*)&out[ob] = make_float4(acc[0], acc[1], acc[2], acc[3]);
  *(float4*)&out[ob + 4] = make_float4(acc[4], acc[5], acc[6], acc[7]);
}

extern "C" void kernel_launch(void* const* d_in, const int* in_sizes, int n_in,
                              void* d_out, int out_size, void* d_ws, size_t ws_size,
                              hipStream_t stream) {
  const float* hs  = (const float*)d_in[0];
  const int*   pos = (const int*)d_in[1];
  const float* ln1 = (const float*)d_in[2];
  const float* ln2 = (const float*)d_in[3];
  const float* wq  = (const float*)d_in[4];
  const float* bq  = (const float*)d_in[5];
  const float* wk  = (const float*)d_in[6];
  const float* bk  = (const float*)d_in[7];
  const float* wv  = (const float*)d_in[8];
  const float* bvp = (const float*)d_in[9];
  const float* wo  = (const float*)d_in[10];
  const float* gw  = (const float*)d_in[11];
  const float* wg  = (const float*)d_in[12];
  const float* wu  = (const float*)d_in[13];
  const float* wd  = (const float*)d_in[14];
  float* out = (float*)d_out;

  const size_t M = 1048576;
  float* ws = (float*)d_ws;
  // ---- dynamic region [0, 14M floats), phase-overlapped ----
  ushort_t* XNb   = (ushort_t*)ws;                  // [0,2M) fl — rms out (both phases)
  ushort_t* QKVp  = (ushort_t*)(ws + 2 * M);        // [2M,8M) fl — 2x 2048x3072 bf16
  ushort_t* Qbh   = (ushort_t*)(ws + 8 * M);        // [8M,10M)
  ushort_t* Kbh   = (ushort_t*)(ws + 10 * M);       // [10M,10.5M)
  ushort_t* Vth   = (ushort_t*)(ws + 10 * M + 524288); // [10.5M,11M)
  ushort_t* ATb   = (ushort_t*)(ws + 11 * M);       // [11M,13M)
  ushort_t* Op    = (ushort_t*)(ws + 2 * M);        // [2M,6M) — 2x 2048x2048 bf16 (QKVp dead)
  float*    XN    = ws + 6 * M;                     // [6M,10M) f32 (Qbh dead at rms2)
  ushort_t* Ag    = (ushort_t*)(ws + 10 * M);       // [10M,14M) — 4096x2048 bf16
  ushort_t* Gp    = (ushort_t*)ws;                  // [0,4M) — 2x 4096x1024 bf16 (after gather)
  ushort_t* Up    = (ushort_t*)(ws + 4 * M);        // [4M,8M)
  ushort_t* FF    = (ushort_t*)(ws + 8 * M);        // [8M,10M) — 4096x1024 bf16
  ushort_t* Yp    = (ushort_t*)ws;                  // [0,8M) — 2x 4096x2048 bf16 (G/U dead)
  // ---- persistent weights [14M, 43M) ----
  ushort_t* wqkvT = (ushort_t*)(ws + 14 * M);       // 3072x2048
  ushort_t* woT   = (ushort_t*)(ws + 17 * M);       // 2048x2048
  ushort_t* wgT   = (ushort_t*)(ws + 19 * M);       // 8x1024x2048
  ushort_t* wuT   = (ushort_t*)(ws + 27 * M);       // 8x1024x2048
  ushort_t* wdT   = (ushort_t*)(ws + 35 * M);       // 8x2048x1024
  // ---- small persistent [43M, ...) ----
  float*    biasC = ws + 43 * M;                    // 3072 f32
  int*      tids  = (int*)(biasC + 4096);
  float*    tws   = (float*)(tids + 4096);
  int*      offs  = (int*)(tws + 4096);
  int*      ptok  = offs + 16;
  int*      sidx  = ptok + 4096;

  // ---- weight pre-pass: transpose + bf16 convert ----
  tcvt_k<<<dim3(64, 64, 1), 256, 0, stream>>>(wq, wqkvT, 2048, 2048, 0, 0);
  tcvt_k<<<dim3(16, 64, 1), 256, 0, stream>>>(wk, wqkvT + (size_t)2048 * 2048, 2048, 512, 0, 0);
  tcvt_k<<<dim3(16, 64, 1), 256, 0, stream>>>(wv, wqkvT + (size_t)2560 * 2048, 2048, 512, 0, 0);
  tcvt_k<<<dim3(64, 64, 1), 256, 0, stream>>>(wo, woT, 2048, 2048, 0, 0);
  tcvt_k<<<dim3(32, 64, 8), 256, 0, stream>>>(wg, wgT, 2048, 1024, 2048L * 1024, 2048L * 1024);
  tcvt_k<<<dim3(32, 64, 8), 256, 0, stream>>>(wu, wuT, 2048, 1024, 2048L * 1024, 2048L * 1024);
  tcvt_k<<<dim3(64, 32, 8), 256, 0, stream>>>(wd, wdT, 1024, 2048, 1024L * 2048, 1024L * 2048);
  bias_concat_k<<<12, 256, 0, stream>>>(bq, bk, bvp, biasC);

  // ---- layer ----
  rmsnorm_k<<<T_, 256, 0, stream>>>(hs, ln1, XNb);
  // QKV projection, split-K x2 -> bf16 partials
  gemm2_k<false, false><<<dim3(32, 24, 1), 256, 0, stream>>>(
      XNb, wqkvT, nullptr, D_, 1024, QKVW_, 0, QKVp, nullptr, (long)T_ * QKVW_, nullptr);
  qkv_prep_k<<<dim3(T_, 6), 256, 0, stream>>>(QKVp, QKVp + (size_t)T_ * QKVW_, biasC, pos,
                                              Qbh, Kbh, Vth);
  attn2_k<<<512, 256, 0, stream>>>(Qbh, Kbh, Vth, ATb);
  // O-projection, split-K x2 -> bf16 partials
  gemm2_k<false, false><<<dim3(32, 16, 1), 256, 0, stream>>>(
      ATb, woT, nullptr, NQ_, 1024, D_, 0, Op, nullptr, (long)T_ * D_, nullptr);
  // h = hs + Op0 + Op1 -> out; rmsnorm2 -> XN, XNb
  rms2_comb_k<<<T_, 256, 0, stream>>>(hs, Op, Op + (size_t)T_ * D_, ln2, out, XN, XNb);
  router_k<<<T_, 256, 0, stream>>>(XN, gw, tids, tws);
  route_build_k<<<1, 256, 0, stream>>>(tids, offs, ptok, sidx);
  gather_k<<<4096, 256, 0, stream>>>(XNb, ptok, Ag);
  // routed gate+up, split-K x2 (DUAL splits grid.y into gate|up)
  gemm2_k<true, true><<<dim3(64, 16, 8), 256, 0, stream>>>(
      Ag, wgT, wuT, D_, 1024, I_, 1024L * 2048, Gp, Up, 4194304L, offs);
  swiglu_k<<<4096, 256, 0, stream>>>(Gp, Up, FF);
  // routed down-proj, split-K x2 -> bf16 partials (slot rows)
  gemm2_k<true, false><<<dim3(64, 16, 8), 256, 0, stream>>>(
      FF, wdT, nullptr, I_, 512, D_, 1024L * 2048, Yp, nullptr, 8388608L, offs);
  moe_combine_k<<<T_, 256, 0, stream>>>(Yp, sidx, tws, out);
}